// Round 1
// baseline (2790.316 us; speedup 1.0000x reference)
//
#include <hip/hip_runtime.h>
#include <cmath>

#define T_SEQ 2048
#define DMODEL 2048
#define NHEADS 8
#define KVHEADS 4
#define HDIM 256
#define WINDOW 1024
#define KM (-2.3819763e38f)

// ---------------------------------------------------------------------------
// Kernel 1: fused QKV projection. C = x @ [q_w | k_w | v_w]
// x: (B*T=4096, 2048) row-major. Weights per head: (D=2048, H=256) row-major.
// Global col c: [0,2048) -> q head c>>8 ; [2048,3072) -> k ; [3072,4096) -> v.
// 64x64 tile, BK=16, 256 threads, 4x4 micro-tile.
// ---------------------------------------------------------------------------
__global__ __launch_bounds__(256) void gemm_qkv(
    const float* __restrict__ x,
    const float* __restrict__ qw, const float* __restrict__ kw,
    const float* __restrict__ vw,
    float* __restrict__ qo, float* __restrict__ ko, float* __restrict__ vo) {
  __shared__ float As[64][17];
  __shared__ float Bs[16][64];
  const int tid = threadIdx.x;
  const int tx = tid & 15, ty = tid >> 4;
  const int c0 = blockIdx.x * 64;
  const int m0 = blockIdx.y * 64;

  const float* wbase;
  float* obase;
  int ldo, cih;
  if (c0 < 2048) {
    wbase = qw + (size_t)(c0 >> 8) * (2048 * 256);
    obase = qo + c0; ldo = 2048; cih = c0 & 255;
  } else if (c0 < 3072) {
    int cc = c0 - 2048;
    wbase = kw + (size_t)(cc >> 8) * (2048 * 256);
    obase = ko + cc; ldo = 1024; cih = cc & 255;
  } else {
    int cc = c0 - 3072;
    wbase = vw + (size_t)(cc >> 8) * (2048 * 256);
    obase = vo + cc; ldo = 1024; cih = cc & 255;
  }

  float4 acc[4];
  acc[0] = acc[1] = acc[2] = acc[3] = make_float4(0.f, 0.f, 0.f, 0.f);

  const int a_m = tid >> 2, a_k = (tid & 3) << 2;
  const int b_k = tid >> 4, b_c = (tid & 15) << 2;

  for (int kt = 0; kt < 2048; kt += 16) {
    float4 av = *(const float4*)&x[(size_t)(m0 + a_m) * 2048 + kt + a_k];
    float4 bv = *(const float4*)&wbase[(size_t)(kt + b_k) * 256 + cih + b_c];
    As[a_m][a_k + 0] = av.x; As[a_m][a_k + 1] = av.y;
    As[a_m][a_k + 2] = av.z; As[a_m][a_k + 3] = av.w;
    *(float4*)&Bs[b_k][b_c] = bv;
    __syncthreads();
#pragma unroll
    for (int kk = 0; kk < 16; ++kk) {
      float4 b4 = *(const float4*)&Bs[kk][tx << 2];
#pragma unroll
      for (int i = 0; i < 4; ++i) {
        float a = As[(ty << 2) + i][kk];
        acc[i].x += a * b4.x; acc[i].y += a * b4.y;
        acc[i].z += a * b4.z; acc[i].w += a * b4.w;
      }
    }
    __syncthreads();
  }
#pragma unroll
  for (int i = 0; i < 4; ++i) {
    int m = m0 + (ty << 2) + i;
    *(float4*)&obase[(size_t)m * ldo + (tx << 2)] = acc[i];
  }
}

// ---------------------------------------------------------------------------
// Kernel 2: in-place RMSNorm + RoPE on q and k rows (one 64-thread wave/row).
// q rows: B*T*N = 32768 ; k rows: B*T*KVHEADS = 16384.
// ---------------------------------------------------------------------------
__global__ __launch_bounds__(64) void rope_norm(
    float* __restrict__ qb, float* __restrict__ kb,
    const int* __restrict__ positions,
    const float* __restrict__ qns, const float* __restrict__ kns) {
  int row = blockIdx.x;
  int lane = threadIdx.x;
  float* ptr; const float* ns; float extra; int bt;
  if (row < 32768) {
    ptr = qb + (size_t)row * 256; ns = qns; extra = 0.0625f; bt = row >> 3;
  } else {
    int r = row - 32768;
    ptr = kb + (size_t)r * 256; ns = kns; extra = 1.0f; bt = r >> 2;
  }
  int pos = positions[bt];  // bt = b*T + t flat, matches positions layout

  float4 xv = *(const float4*)&ptr[lane << 2];
  float ss = xv.x * xv.x + xv.y * xv.y + xv.z * xv.z + xv.w * xv.w;
#pragma unroll
  for (int off = 1; off < 64; off <<= 1) ss += __shfl_xor(ss, off, 64);
  float rinv = rsqrtf(ss * (1.0f / 256.0f) + 1e-6f);

  float4 sc4 = *(const float4*)&ns[lane << 2];
  xv.x *= rinv * (1.0f + sc4.x);
  xv.y *= rinv * (1.0f + sc4.y);
  xv.z *= rinv * (1.0f + sc4.z);
  xv.w *= rinv * (1.0f + sc4.w);

  float4 ov;
  ov.x = __shfl_xor(xv.x, 32, 64);
  ov.y = __shfl_xor(xv.y, 32, 64);
  ov.z = __shfl_xor(xv.z, 32, 64);
  ov.w = __shfl_xor(xv.w, 32, 64);

  int hr = (lane & 31) << 2;
  float sgn = (lane < 32) ? -1.0f : 1.0f;
  float own[4] = {xv.x, xv.y, xv.z, xv.w};
  float oth[4] = {ov.x, ov.y, ov.z, ov.w};
  float res[4];
#pragma unroll
  for (int c = 0; c < 4; ++c) {
    // inv timescale = 10000^(-(hr+c)/128) = 2^(-(hr+c)*log2(10000)/128)
    float invts = exp2f(-(float)(hr + c) * 0.10381025296523007f);
    float angle = (float)pos * invts;
    float sn, cs;
    sincosf(angle, &sn, &cs);
    res[c] = (own[c] * cs + sgn * oth[c] * sn) * extra;
  }
  float4 r4 = make_float4(res[0], res[1], res[2], res[3]);
  *(float4*)&ptr[lane << 2] = r4;
}

// ---------------------------------------------------------------------------
// Kernel 3: sliding-window attention, flash-style online softmax.
// Block = (t-tile of 16, head n, batch b). 256 threads.
// Q/K tiles padded to stride 260 (bank 4-stagger), V stride 256 (contig reads).
// ---------------------------------------------------------------------------
__global__ __launch_bounds__(256) void attn_kernel(
    const float* __restrict__ q, const float* __restrict__ k,
    const float* __restrict__ v, float* __restrict__ o) {
  __shared__ float Qs[16][260];
  __shared__ float Ks[16][260];
  __shared__ float Vs[16][256];
  __shared__ float S[16][16];
  __shared__ float mrow[16], lrow[16], arow[16];

  const int tid = threadIdx.x;
  const int t0 = blockIdx.x * 16;
  const int n = blockIdx.y;
  const int b = blockIdx.z;
  const int kvh = n >> 1;  // G = 2 query heads per kv head

  // stage Q tile
  {
    int i = tid >> 4, c0 = (tid & 15) << 2;
    const float* qp = q + (((size_t)b * T_SEQ + t0 + i) * NHEADS + n) * HDIM;
#pragma unroll
    for (int c = 0; c < 4; ++c)
      *(float4*)&Qs[i][c0 + 64 * c] = *(const float4*)&qp[c0 + 64 * c];
  }
  if (tid < 16) { mrow[tid] = KM; lrow[tid] = 0.f; }

  float4 acc[4];
  acc[0] = acc[1] = acc[2] = acc[3] = make_float4(0.f, 0.f, 0.f, 0.f);
  const int rg = tid >> 6;          // wave id -> rows rg*4..rg*4+3
  const int h4 = (tid & 63) << 2;   // h offset for PV/store
  const int qi = tid >> 4, qj = tid & 15;

  int s_begin = t0 - 1024; if (s_begin < 0) s_begin = 0;
  __syncthreads();

  for (int s0 = s_begin; s0 <= t0 + 15; s0 += 16) {
    // stage K,V tiles
    {
      int j = tid >> 4, c0 = (tid & 15) << 2;
      const float* kp = k + (((size_t)b * T_SEQ + s0 + j) * KVHEADS + kvh) * HDIM;
      const float* vp = v + (((size_t)b * T_SEQ + s0 + j) * KVHEADS + kvh) * HDIM;
#pragma unroll
      for (int c = 0; c < 4; ++c) {
        *(float4*)&Ks[j][c0 + 64 * c] = *(const float4*)&kp[c0 + 64 * c];
        *(float4*)&Vs[j][c0 + 64 * c] = *(const float4*)&vp[c0 + 64 * c];
      }
    }
    __syncthreads();

    // QK^T: one score per thread
    float sc = 0.f;
#pragma unroll 8
    for (int kk = 0; kk < 256; kk += 4) {
      float4 q4 = *(const float4*)&Qs[qi][kk];
      float4 k4 = *(const float4*)&Ks[qj][kk];
      sc += q4.x * k4.x + q4.y * k4.y + q4.z * k4.z + q4.w * k4.w;
    }
    int tpos = t0 + qi, spos = s0 + qj;
    bool valid = (spos <= tpos) && (spos + WINDOW > tpos);
    S[qi][qj] = valid ? sc : KM;
    __syncthreads();

    // online softmax (row-serial, 16 threads)
    if (tid < 16) {
      int i = tid;
      float mold = mrow[i], mt = mold;
#pragma unroll
      for (int j = 0; j < 16; ++j) mt = fmaxf(mt, S[i][j]);
      float al = __expf(mold - mt);
      float sum = 0.f;
#pragma unroll
      for (int j = 0; j < 16; ++j) {
        float p = __expf(S[i][j] - mt);
        S[i][j] = p;
        sum += p;
      }
      mrow[i] = mt;
      lrow[i] = lrow[i] * al + sum;
      arow[i] = al;
    }
    __syncthreads();

    // PV: rescale accumulators, then accumulate this tile
#pragma unroll
    for (int ii = 0; ii < 4; ++ii) {
      float al = arow[rg * 4 + ii];
      acc[ii].x *= al; acc[ii].y *= al; acc[ii].z *= al; acc[ii].w *= al;
    }
#pragma unroll
    for (int j = 0; j < 16; ++j) {
      float4 v4 = *(const float4*)&Vs[j][h4];
#pragma unroll
      for (int ii = 0; ii < 4; ++ii) {
        float p = S[rg * 4 + ii][j];
        acc[ii].x += p * v4.x; acc[ii].y += p * v4.y;
        acc[ii].z += p * v4.z; acc[ii].w += p * v4.w;
      }
    }
    __syncthreads();
  }

#pragma unroll
  for (int ii = 0; ii < 4; ++ii) {
    int i = rg * 4 + ii;
    float inv = 1.0f / lrow[i];
    float4 a = acc[ii];
    a.x *= inv; a.y *= inv; a.z *= inv; a.w *= inv;
    *(float4*)&o[(((size_t)b * T_SEQ + t0 + i) * NHEADS + n) * HDIM + h4] = a;
  }
}

// ---------------------------------------------------------------------------
// Kernel 4: output projection. out = attn(4096 x 2048) @ o_w(2048 x 2048)
// o_w (N,H,D) flat == row-major (N*H, D), matching attn's (.., n, h) flattening.
// ---------------------------------------------------------------------------
__global__ __launch_bounds__(256) void gemm_out(
    const float* __restrict__ attn, const float* __restrict__ ow,
    float* __restrict__ out) {
  __shared__ float As[64][17];
  __shared__ float Bs[16][64];
  const int tid = threadIdx.x;
  const int tx = tid & 15, ty = tid >> 4;
  const int c0 = blockIdx.x * 64;
  const int m0 = blockIdx.y * 64;

  float4 acc[4];
  acc[0] = acc[1] = acc[2] = acc[3] = make_float4(0.f, 0.f, 0.f, 0.f);

  const int a_m = tid >> 2, a_k = (tid & 3) << 2;
  const int b_k = tid >> 4, b_c = (tid & 15) << 2;

  for (int kt = 0; kt < 2048; kt += 16) {
    float4 av = *(const float4*)&attn[(size_t)(m0 + a_m) * 2048 + kt + a_k];
    float4 bv = *(const float4*)&ow[(size_t)(kt + b_k) * 2048 + c0 + b_c];
    As[a_m][a_k + 0] = av.x; As[a_m][a_k + 1] = av.y;
    As[a_m][a_k + 2] = av.z; As[a_m][a_k + 3] = av.w;
    *(float4*)&Bs[b_k][b_c] = bv;
    __syncthreads();
#pragma unroll
    for (int kk = 0; kk < 16; ++kk) {
      float4 b4 = *(const float4*)&Bs[kk][tx << 2];
#pragma unroll
      for (int i = 0; i < 4; ++i) {
        float a = As[(ty << 2) + i][kk];
        acc[i].x += a * b4.x; acc[i].y += a * b4.y;
        acc[i].z += a * b4.z; acc[i].w += a * b4.w;
      }
    }
    __syncthreads();
  }
#pragma unroll
  for (int i = 0; i < 4; ++i) {
    int m = m0 + (ty << 2) + i;
    *(float4*)&out[(size_t)m * 2048 + c0 + (tx << 2)] = acc[i];
  }
}

extern "C" void kernel_launch(void* const* d_in, const int* in_sizes, int n_in,
                              void* d_out, int out_size, void* d_ws, size_t ws_size,
                              hipStream_t stream) {
  const float* x   = (const float*)d_in[0];
  const int* pos   = (const int*)d_in[1];
  const float* q_w = (const float*)d_in[2];
  const float* k_w = (const float*)d_in[3];
  const float* v_w = (const float*)d_in[4];
  const float* o_w = (const float*)d_in[5];
  const float* qns = (const float*)d_in[6];
  const float* kns = (const float*)d_in[7];
  float* out = (float*)d_out;

  float* ws = (float*)d_ws;
  float* qbuf = ws;                       // 2*2048*8*256   = 8388608
  float* kbuf = ws + 8388608;             // 2*2048*4*256   = 4194304
  float* vbuf = ws + 12582912;            // 4194304
  float* abuf = ws + 16777216;            // 8388608

  gemm_qkv<<<dim3(64, 64, 1), 256, 0, stream>>>(x, q_w, k_w, v_w, qbuf, kbuf, vbuf);
  rope_norm<<<dim3(49152, 1, 1), 64, 0, stream>>>(qbuf, kbuf, pos, qns, kns);
  attn_kernel<<<dim3(128, 8, 2), 256, 0, stream>>>(qbuf, kbuf, vbuf, abuf);
  gemm_out<<<dim3(32, 64, 1), 256, 0, stream>>>(abuf, o_w, out);
}

// Round 2
// 1160.681 us; speedup vs baseline: 2.4040x; 2.4040x over previous
//
#include <hip/hip_runtime.h>
#include <cmath>

#define T_SEQ 2048
#define DMODEL 2048
#define NHEADS 8
#define KVHEADS 4
#define HDIM 256
#define WINDOW 1024
#define KM (-2.3819763e38f)

typedef __attribute__((ext_vector_type(8))) short bf16x8;
typedef __attribute__((ext_vector_type(4))) float f32x4;

__device__ __forceinline__ unsigned short f2bf(float f) {
  union { float f; unsigned int u; } v; v.f = f;
  unsigned int r = v.u + 0x7FFFu + ((v.u >> 16) & 1u);  // RNE
  return (unsigned short)(r >> 16);
}

#define GLD16(gp, lp)                                                  \
  __builtin_amdgcn_global_load_lds(                                    \
      (__attribute__((address_space(1))) unsigned int*)(gp),           \
      (__attribute__((address_space(3))) unsigned int*)(lp), 16, 0, 0)

// ---------------------------------------------------------------------------
// cast x (fp32) -> bf16, 4 elems/thread
// ---------------------------------------------------------------------------
__global__ __launch_bounds__(256) void cast_bf16(const float* __restrict__ in,
                                                 unsigned short* __restrict__ out) {
  size_t i = (size_t)blockIdx.x * 256 + threadIdx.x;
  float4 v = *(const float4*)&in[i * 4];
  ushort4 o;
  o.x = f2bf(v.x); o.y = f2bf(v.y); o.z = f2bf(v.z); o.w = f2bf(v.w);
  *(ushort4*)&out[i * 4] = o;
}

// ---------------------------------------------------------------------------
// Build Bt (4096 x 2048) bf16: Bt[c][d] = w[head(c)][d][h(c)] for q|k|v cols.
// 64x64 tile transpose via LDS.
// ---------------------------------------------------------------------------
__global__ __launch_bounds__(256) void transpose_wqkv(
    const float* __restrict__ qw, const float* __restrict__ kw,
    const float* __restrict__ vw, unsigned short* __restrict__ bt) {
  __shared__ float tile[64][65];
  int c0 = blockIdx.x * 64;  // output row base (col of logical B)
  int d0 = blockIdx.y * 64;
  const float* src; int hbase;
  if (c0 < 2048) { src = qw + (size_t)(c0 >> 8) * 524288; hbase = c0 & 255; }
  else if (c0 < 3072) { int cc = c0 - 2048; src = kw + (size_t)(cc >> 8) * 524288; hbase = cc & 255; }
  else { int cc = c0 - 3072; src = vw + (size_t)(cc >> 8) * 524288; hbase = cc & 255; }
  int tx = threadIdx.x & 15, ty = threadIdx.x >> 4;
#pragma unroll
  for (int p = 0; p < 4; ++p) {
    float4 v = *(const float4*)&src[(size_t)(d0 + ty + 16 * p) * 256 + hbase + tx * 4];
    tile[ty + 16 * p][tx * 4 + 0] = v.x; tile[ty + 16 * p][tx * 4 + 1] = v.y;
    tile[ty + 16 * p][tx * 4 + 2] = v.z; tile[ty + 16 * p][tx * 4 + 3] = v.w;
  }
  __syncthreads();
#pragma unroll
  for (int p = 0; p < 4; ++p) {
    int hh = ty + 16 * p;
    ushort4 o;
    o.x = f2bf(tile[tx * 4 + 0][hh]); o.y = f2bf(tile[tx * 4 + 1][hh]);
    o.z = f2bf(tile[tx * 4 + 2][hh]); o.w = f2bf(tile[tx * 4 + 3][hh]);
    *(ushort4*)&bt[(size_t)(c0 + hh) * 2048 + d0 + tx * 4] = o;
  }
}

// ---------------------------------------------------------------------------
// Build wot (2048 x 2048) bf16: wot[d][j] = o_w[j][d]  (j = n*256+h)
// ---------------------------------------------------------------------------
__global__ __launch_bounds__(256) void transpose_wo(
    const float* __restrict__ ow, unsigned short* __restrict__ wot) {
  __shared__ float tile[64][65];
  int j0 = blockIdx.x * 64;
  int d0 = blockIdx.y * 64;
  int tx = threadIdx.x & 15, ty = threadIdx.x >> 4;
#pragma unroll
  for (int p = 0; p < 4; ++p) {
    float4 v = *(const float4*)&ow[(size_t)(j0 + ty + 16 * p) * 2048 + d0 + tx * 4];
    tile[ty + 16 * p][tx * 4 + 0] = v.x; tile[ty + 16 * p][tx * 4 + 1] = v.y;
    tile[ty + 16 * p][tx * 4 + 2] = v.z; tile[ty + 16 * p][tx * 4 + 3] = v.w;
  }
  __syncthreads();
#pragma unroll
  for (int p = 0; p < 4; ++p) {
    int hh = ty + 16 * p;
    ushort4 o;
    o.x = f2bf(tile[tx * 4 + 0][hh]); o.y = f2bf(tile[tx * 4 + 1][hh]);
    o.z = f2bf(tile[tx * 4 + 2][hh]); o.w = f2bf(tile[tx * 4 + 3][hh]);
    *(ushort4*)&wot[(size_t)(d0 + hh) * 2048 + j0 + tx * 4] = o;
  }
}

// ---------------------------------------------------------------------------
// m97-style bf16 MFMA GEMM core: C(128x128) = A(MxK) @ Bt(NxK)^T
// 256 threads = 4 waves in 2x2 grid of 64x64; 16x16x32 MFMA, BK=32,
// global_load_lds width-16 staging.
// ---------------------------------------------------------------------------
__device__ __forceinline__ void gemm128_core(
    const unsigned short* __restrict__ A, const unsigned short* __restrict__ Bt,
    unsigned short* As, unsigned short* Bs, int m0, int n0, int K,
    f32x4 acc[4][4]) {
  const int tid = threadIdx.x;
  const int wave = tid >> 6, lane = tid & 63;
  const int wm = (wave & 1) << 6, wn = (wave >> 1) << 6;
  const int i0 = wave * 2, i1 = wave * 2 + 1;
  const int sr = lane >> 2;
  const int sc = (lane & 3) * 8;
  const size_t ar0 = (size_t)(m0 + i0 * 16 + sr) * K + sc;
  const size_t ar1 = (size_t)(m0 + i1 * 16 + sr) * K + sc;
  const size_t br0 = (size_t)(n0 + i0 * 16 + sr) * K + sc;
  const size_t br1 = (size_t)(n0 + i1 * 16 + sr) * K + sc;
  const int fm = lane & 15, fk = (lane >> 4) * 8;

  for (int kt = 0; kt < K; kt += 32) {
    GLD16(A + ar0 + kt, As + i0 * 512);
    GLD16(A + ar1 + kt, As + i1 * 512);
    GLD16(Bt + br0 + kt, Bs + i0 * 512);
    GLD16(Bt + br1 + kt, Bs + i1 * 512);
    __syncthreads();
    bf16x8 af[4], bv[4];
#pragma unroll
    for (int i = 0; i < 4; ++i)
      af[i] = *(const bf16x8*)&As[(wm + i * 16 + fm) * 32 + fk];
#pragma unroll
    for (int j = 0; j < 4; ++j)
      bv[j] = *(const bf16x8*)&Bs[(wn + j * 16 + fm) * 32 + fk];
#pragma unroll
    for (int i = 0; i < 4; ++i)
#pragma unroll
      for (int j = 0; j < 4; ++j)
        acc[i][j] = __builtin_amdgcn_mfma_f32_16x16x32_bf16(af[i], bv[j], acc[i][j], 0, 0, 0);
    __syncthreads();
  }
}

// QKV projection: xb(4096x2048) @ wt(4096x2048)^T -> q/k/v fp32
__global__ __launch_bounds__(256) void gemm_qkv_bf16(
    const unsigned short* __restrict__ xb, const unsigned short* __restrict__ wt,
    float* __restrict__ qo, float* __restrict__ ko, float* __restrict__ vo) {
  __shared__ unsigned short As[128 * 32];
  __shared__ unsigned short Bs[128 * 32];
  const int n0 = blockIdx.x * 128, m0 = blockIdx.y * 128;
  f32x4 acc[4][4];
#pragma unroll
  for (int i = 0; i < 4; ++i)
#pragma unroll
    for (int j = 0; j < 4; ++j) acc[i][j] = {0.f, 0.f, 0.f, 0.f};
  gemm128_core(xb, wt, As, Bs, m0, n0, 2048, acc);

  float* obase; int ldo, cb;
  if (n0 < 2048) { obase = qo; ldo = 2048; cb = n0; }
  else if (n0 < 3072) { obase = ko; ldo = 1024; cb = n0 - 2048; }
  else { obase = vo; ldo = 1024; cb = n0 - 3072; }
  const int lane = threadIdx.x & 63, wave = threadIdx.x >> 6;
  const int wm = (wave & 1) << 6, wn = (wave >> 1) << 6;
  const int rbase = m0 + wm + (lane >> 4) * 4;
  const int cbase = cb + wn + (lane & 15);
#pragma unroll
  for (int i = 0; i < 4; ++i)
#pragma unroll
    for (int j = 0; j < 4; ++j)
#pragma unroll
      for (int r = 0; r < 4; ++r)
        obase[(size_t)(rbase + i * 16 + r) * ldo + cbase + j * 16] = acc[i][j][r];
}

// Output projection: abuf(4096x2048 bf16) @ wot(2048x2048)^T -> out fp32
__global__ __launch_bounds__(256) void gemm_out_bf16(
    const unsigned short* __restrict__ ab, const unsigned short* __restrict__ wot,
    float* __restrict__ out) {
  __shared__ unsigned short As[128 * 32];
  __shared__ unsigned short Bs[128 * 32];
  const int n0 = blockIdx.x * 128, m0 = blockIdx.y * 128;
  f32x4 acc[4][4];
#pragma unroll
  for (int i = 0; i < 4; ++i)
#pragma unroll
    for (int j = 0; j < 4; ++j) acc[i][j] = {0.f, 0.f, 0.f, 0.f};
  gemm128_core(ab, wot, As, Bs, m0, n0, 2048, acc);

  const int lane = threadIdx.x & 63, wave = threadIdx.x >> 6;
  const int wm = (wave & 1) << 6, wn = (wave >> 1) << 6;
  const int rbase = m0 + wm + (lane >> 4) * 4;
  const int cbase = n0 + wn + (lane & 15);
#pragma unroll
  for (int i = 0; i < 4; ++i)
#pragma unroll
    for (int j = 0; j < 4; ++j)
#pragma unroll
      for (int r = 0; r < 4; ++r)
        out[(size_t)(rbase + i * 16 + r) * 2048 + cbase + j * 16] = acc[i][j][r];
}

// ---------------------------------------------------------------------------
// RMSNorm + RoPE on q and k rows (one 64-thread wave/row), fp32 in-place.
// ---------------------------------------------------------------------------
__global__ __launch_bounds__(64) void rope_norm(
    float* __restrict__ qb, float* __restrict__ kb,
    const int* __restrict__ positions,
    const float* __restrict__ qns, const float* __restrict__ kns) {
  int row = blockIdx.x;
  int lane = threadIdx.x;
  float* ptr; const float* ns; float extra; int bt;
  if (row < 32768) {
    ptr = qb + (size_t)row * 256; ns = qns; extra = 0.0625f; bt = row >> 3;
  } else {
    int r = row - 32768;
    ptr = kb + (size_t)r * 256; ns = kns; extra = 1.0f; bt = r >> 2;
  }
  int pos = positions[bt];

  float4 xv = *(const float4*)&ptr[lane << 2];
  float ss = xv.x * xv.x + xv.y * xv.y + xv.z * xv.z + xv.w * xv.w;
#pragma unroll
  for (int off = 1; off < 64; off <<= 1) ss += __shfl_xor(ss, off, 64);
  float rinv = rsqrtf(ss * (1.0f / 256.0f) + 1e-6f);

  float4 sc4 = *(const float4*)&ns[lane << 2];
  xv.x *= rinv * (1.0f + sc4.x);
  xv.y *= rinv * (1.0f + sc4.y);
  xv.z *= rinv * (1.0f + sc4.z);
  xv.w *= rinv * (1.0f + sc4.w);

  float4 ov;
  ov.x = __shfl_xor(xv.x, 32, 64);
  ov.y = __shfl_xor(xv.y, 32, 64);
  ov.z = __shfl_xor(xv.z, 32, 64);
  ov.w = __shfl_xor(xv.w, 32, 64);

  int hr = (lane & 31) << 2;
  float sgn = (lane < 32) ? -1.0f : 1.0f;
  float own[4] = {xv.x, xv.y, xv.z, xv.w};
  float oth[4] = {ov.x, ov.y, ov.z, ov.w};
  float res[4];
#pragma unroll
  for (int c = 0; c < 4; ++c) {
    float invts = exp2f(-(float)(hr + c) * 0.10381025296523007f);
    float angle = (float)pos * invts;
    float sn, cs;
    sincosf(angle, &sn, &cs);
    res[c] = (own[c] * cs + sgn * oth[c] * sn) * extra;
  }
  *(float4*)&ptr[lane << 2] = make_float4(res[0], res[1], res[2], res[3]);
}

// ---------------------------------------------------------------------------
// Sliding-window attention, flash-style online softmax (fp32, bf16 output).
// ---------------------------------------------------------------------------
__global__ __launch_bounds__(256) void attn_kernel(
    const float* __restrict__ q, const float* __restrict__ k,
    const float* __restrict__ v, unsigned short* __restrict__ o) {
  __shared__ float Qs[16][260];
  __shared__ float Ks[16][260];
  __shared__ float Vs[16][256];
  __shared__ float S[16][16];
  __shared__ float mrow[16], lrow[16], arow[16];

  const int tid = threadIdx.x;
  const int t0 = blockIdx.x * 16;
  const int n = blockIdx.y;
  const int b = blockIdx.z;
  const int kvh = n >> 1;

  {
    int i = tid >> 4, c0 = (tid & 15) << 2;
    const float* qp = q + (((size_t)b * T_SEQ + t0 + i) * NHEADS + n) * HDIM;
#pragma unroll
    for (int c = 0; c < 4; ++c)
      *(float4*)&Qs[i][c0 + 64 * c] = *(const float4*)&qp[c0 + 64 * c];
  }
  if (tid < 16) { mrow[tid] = KM; lrow[tid] = 0.f; }

  float4 acc[4];
  acc[0] = acc[1] = acc[2] = acc[3] = make_float4(0.f, 0.f, 0.f, 0.f);
  const int rg = tid >> 6;
  const int h4 = (tid & 63) << 2;
  const int qi = tid >> 4, qj = tid & 15;

  int s_begin = t0 - 1024; if (s_begin < 0) s_begin = 0;
  __syncthreads();

  for (int s0 = s_begin; s0 <= t0 + 15; s0 += 16) {
    {
      int j = tid >> 4, c0 = (tid & 15) << 2;
      const float* kp = k + (((size_t)b * T_SEQ + s0 + j) * KVHEADS + kvh) * HDIM;
      const float* vp = v + (((size_t)b * T_SEQ + s0 + j) * KVHEADS + kvh) * HDIM;
#pragma unroll
      for (int c = 0; c < 4; ++c) {
        *(float4*)&Ks[j][c0 + 64 * c] = *(const float4*)&kp[c0 + 64 * c];
        *(float4*)&Vs[j][c0 + 64 * c] = *(const float4*)&vp[c0 + 64 * c];
      }
    }
    __syncthreads();

    float sc = 0.f;
#pragma unroll 8
    for (int kk = 0; kk < 256; kk += 4) {
      float4 q4 = *(const float4*)&Qs[qi][kk];
      float4 k4 = *(const float4*)&Ks[qj][kk];
      sc += q4.x * k4.x + q4.y * k4.y + q4.z * k4.z + q4.w * k4.w;
    }
    int tpos = t0 + qi, spos = s0 + qj;
    bool valid = (spos <= tpos) && (spos + WINDOW > tpos);
    S[qi][qj] = valid ? sc : KM;
    __syncthreads();

    if (tid < 16) {
      int i = tid;
      float mold = mrow[i], mt = mold;
#pragma unroll
      for (int j = 0; j < 16; ++j) mt = fmaxf(mt, S[i][j]);
      float al = __expf(mold - mt);
      float sum = 0.f;
#pragma unroll
      for (int j = 0; j < 16; ++j) {
        float p = __expf(S[i][j] - mt);
        S[i][j] = p;
        sum += p;
      }
      mrow[i] = mt;
      lrow[i] = lrow[i] * al + sum;
      arow[i] = al;
    }
    __syncthreads();

#pragma unroll
    for (int ii = 0; ii < 4; ++ii) {
      float al = arow[rg * 4 + ii];
      acc[ii].x *= al; acc[ii].y *= al; acc[ii].z *= al; acc[ii].w *= al;
    }
#pragma unroll
    for (int j = 0; j < 16; ++j) {
      float4 v4 = *(const float4*)&Vs[j][h4];
#pragma unroll
      for (int ii = 0; ii < 4; ++ii) {
        float p = S[rg * 4 + ii][j];
        acc[ii].x += p * v4.x; acc[ii].y += p * v4.y;
        acc[ii].z += p * v4.z; acc[ii].w += p * v4.w;
      }
    }
    __syncthreads();
  }

#pragma unroll
  for (int ii = 0; ii < 4; ++ii) {
    int i = rg * 4 + ii;
    float inv = 1.0f / lrow[i];
    float4 a = acc[ii];
    ushort4 o4;
    o4.x = f2bf(a.x * inv); o4.y = f2bf(a.y * inv);
    o4.z = f2bf(a.z * inv); o4.w = f2bf(a.w * inv);
    *(ushort4*)&o[(((size_t)b * T_SEQ + t0 + i) * NHEADS + n) * HDIM + h4] = o4;
  }
}

extern "C" void kernel_launch(void* const* d_in, const int* in_sizes, int n_in,
                              void* d_out, int out_size, void* d_ws, size_t ws_size,
                              hipStream_t stream) {
  const float* x   = (const float*)d_in[0];
  const int* pos   = (const int*)d_in[1];
  const float* q_w = (const float*)d_in[2];
  const float* k_w = (const float*)d_in[3];
  const float* v_w = (const float*)d_in[4];
  const float* o_w = (const float*)d_in[5];
  const float* qns = (const float*)d_in[6];
  const float* kns = (const float*)d_in[7];
  float* out = (float*)d_out;

  float* ws = (float*)d_ws;
  float* qbuf = ws;                        // 8,388,608 f
  float* kbuf = qbuf + 8388608;            // 4,194,304 f
  float* vbuf = kbuf + 4194304;            // 4,194,304 f
  unsigned short* xb    = (unsigned short*)(vbuf + 4194304);  // 8,388,608 us
  unsigned short* abuf  = xb;                                  // reuse after gemm_qkv
  unsigned short* wqkvt = xb + 8388608;                        // 8,388,608 us
  unsigned short* wot   = wqkvt;                               // reuse after gemm_qkv

  cast_bf16<<<dim3(8192), 256, 0, stream>>>(x, xb);
  transpose_wqkv<<<dim3(64, 32), 256, 0, stream>>>(q_w, k_w, v_w, wqkvt);
  gemm_qkv_bf16<<<dim3(32, 32), 256, 0, stream>>>(xb, wqkvt, qbuf, kbuf, vbuf);
  transpose_wo<<<dim3(32, 32), 256, 0, stream>>>(o_w, wot);
  rope_norm<<<dim3(49152), 64, 0, stream>>>(qbuf, kbuf, pos, qns, kns);
  attn_kernel<<<dim3(128, 8, 2), 256, 0, stream>>>(qbuf, kbuf, vbuf, abuf);
  gemm_out_bf16<<<dim3(16, 32), 256, 0, stream>>>(abuf, wot, out);
}

// Round 3
// 395.833 us; speedup vs baseline: 7.0492x; 2.9323x over previous
//
#include <hip/hip_runtime.h>
#include <cmath>

#define T_SEQ 2048
#define WINDOW 1024

typedef __attribute__((ext_vector_type(8))) short bf16x8;
typedef __attribute__((ext_vector_type(4))) float f32x4;
typedef __attribute__((ext_vector_type(16))) float f32x16;

__device__ __forceinline__ unsigned short f2bf(float f) {
  union { float f; unsigned int u; } v; v.f = f;
  unsigned int r = v.u + 0x7FFFu + ((v.u >> 16) & 1u);  // RNE
  return (unsigned short)(r >> 16);
}
__device__ __forceinline__ float bf2f(unsigned short u) {
  union { unsigned int i; float f; } v; v.i = ((unsigned int)u) << 16;
  return v.f;
}

#define GLD16(gp, lp)                                                  \
  __builtin_amdgcn_global_load_lds(                                    \
      (__attribute__((address_space(1))) unsigned int*)(gp),           \
      (__attribute__((address_space(3))) unsigned int*)(lp), 16, 0, 0)

// ---------------------------------------------------------------------------
// cast x (fp32) -> bf16
// ---------------------------------------------------------------------------
__global__ __launch_bounds__(256) void cast_bf16(const float* __restrict__ in,
                                                 unsigned short* __restrict__ out) {
  size_t i = (size_t)blockIdx.x * 256 + threadIdx.x;
  float4 v = *(const float4*)&in[i * 4];
  ushort4 o;
  o.x = f2bf(v.x); o.y = f2bf(v.y); o.z = f2bf(v.z); o.w = f2bf(v.w);
  *(ushort4*)&out[i * 4] = o;
}

// ---------------------------------------------------------------------------
// Bt (4096 x 2048) bf16: Bt[c][d] = w[head(c)][d][h(c)] for q|k|v cols.
// ---------------------------------------------------------------------------
__global__ __launch_bounds__(256) void transpose_wqkv(
    const float* __restrict__ qw, const float* __restrict__ kw,
    const float* __restrict__ vw, unsigned short* __restrict__ bt) {
  __shared__ float tile[64][65];
  int c0 = blockIdx.x * 64;
  int d0 = blockIdx.y * 64;
  const float* src; int hbase;
  if (c0 < 2048) { src = qw + (size_t)(c0 >> 8) * 524288; hbase = c0 & 255; }
  else if (c0 < 3072) { int cc = c0 - 2048; src = kw + (size_t)(cc >> 8) * 524288; hbase = cc & 255; }
  else { int cc = c0 - 3072; src = vw + (size_t)(cc >> 8) * 524288; hbase = cc & 255; }
  int tx = threadIdx.x & 15, ty = threadIdx.x >> 4;
#pragma unroll
  for (int p = 0; p < 4; ++p) {
    float4 v = *(const float4*)&src[(size_t)(d0 + ty + 16 * p) * 256 + hbase + tx * 4];
    tile[ty + 16 * p][tx * 4 + 0] = v.x; tile[ty + 16 * p][tx * 4 + 1] = v.y;
    tile[ty + 16 * p][tx * 4 + 2] = v.z; tile[ty + 16 * p][tx * 4 + 3] = v.w;
  }
  __syncthreads();
#pragma unroll
  for (int p = 0; p < 4; ++p) {
    int hh = ty + 16 * p;
    ushort4 o;
    o.x = f2bf(tile[tx * 4 + 0][hh]); o.y = f2bf(tile[tx * 4 + 1][hh]);
    o.z = f2bf(tile[tx * 4 + 2][hh]); o.w = f2bf(tile[tx * 4 + 3][hh]);
    *(ushort4*)&bt[(size_t)(c0 + hh) * 2048 + d0 + tx * 4] = o;
  }
}

// ---------------------------------------------------------------------------
// wot (2048 x 2048) bf16: wot[d][j] = o_w[j][d]  (j = n*256+h)
// ---------------------------------------------------------------------------
__global__ __launch_bounds__(256) void transpose_wo(
    const float* __restrict__ ow, unsigned short* __restrict__ wot) {
  __shared__ float tile[64][65];
  int j0 = blockIdx.x * 64;
  int d0 = blockIdx.y * 64;
  int tx = threadIdx.x & 15, ty = threadIdx.x >> 4;
#pragma unroll
  for (int p = 0; p < 4; ++p) {
    float4 v = *(const float4*)&ow[(size_t)(j0 + ty + 16 * p) * 2048 + d0 + tx * 4];
    tile[ty + 16 * p][tx * 4 + 0] = v.x; tile[ty + 16 * p][tx * 4 + 1] = v.y;
    tile[ty + 16 * p][tx * 4 + 2] = v.z; tile[ty + 16 * p][tx * 4 + 3] = v.w;
  }
  __syncthreads();
#pragma unroll
  for (int p = 0; p < 4; ++p) {
    int hh = ty + 16 * p;
    ushort4 o;
    o.x = f2bf(tile[tx * 4 + 0][hh]); o.y = f2bf(tile[tx * 4 + 1][hh]);
    o.z = f2bf(tile[tx * 4 + 2][hh]); o.w = f2bf(tile[tx * 4 + 3][hh]);
    *(ushort4*)&wot[(size_t)(d0 + hh) * 2048 + j0 + tx * 4] = o;
  }
}

// ---------------------------------------------------------------------------
// m97-style bf16 MFMA GEMM core (16x16x32), 128x128 tile.
// ---------------------------------------------------------------------------
__device__ __forceinline__ void gemm128_core(
    const unsigned short* __restrict__ A, const unsigned short* __restrict__ Bt,
    unsigned short* As, unsigned short* Bs, int m0, int n0, int K,
    f32x4 acc[4][4]) {
  const int tid = threadIdx.x;
  const int wave = tid >> 6, lane = tid & 63;
  const int wm = (wave & 1) << 6, wn = (wave >> 1) << 6;
  const int i0 = wave * 2, i1 = wave * 2 + 1;
  const int sr = lane >> 2;
  const int sc = (lane & 3) * 8;
  const size_t ar0 = (size_t)(m0 + i0 * 16 + sr) * K + sc;
  const size_t ar1 = (size_t)(m0 + i1 * 16 + sr) * K + sc;
  const size_t br0 = (size_t)(n0 + i0 * 16 + sr) * K + sc;
  const size_t br1 = (size_t)(n0 + i1 * 16 + sr) * K + sc;
  const int fm = lane & 15, fk = (lane >> 4) * 8;

  for (int kt = 0; kt < K; kt += 32) {
    GLD16(A + ar0 + kt, As + i0 * 512);
    GLD16(A + ar1 + kt, As + i1 * 512);
    GLD16(Bt + br0 + kt, Bs + i0 * 512);
    GLD16(Bt + br1 + kt, Bs + i1 * 512);
    __syncthreads();
    bf16x8 af[4], bv[4];
#pragma unroll
    for (int i = 0; i < 4; ++i)
      af[i] = *(const bf16x8*)&As[(wm + i * 16 + fm) * 32 + fk];
#pragma unroll
    for (int j = 0; j < 4; ++j)
      bv[j] = *(const bf16x8*)&Bs[(wn + j * 16 + fm) * 32 + fk];
#pragma unroll
    for (int i = 0; i < 4; ++i)
#pragma unroll
      for (int j = 0; j < 4; ++j)
        acc[i][j] = __builtin_amdgcn_mfma_f32_16x16x32_bf16(af[i], bv[j], acc[i][j], 0, 0, 0);
    __syncthreads();
  }
}

// QKV projection -> bf16 outputs qb0[b][t][8][256], kb0[b][t][4][256], vbf[b][t][4][256]
__global__ __launch_bounds__(256) void gemm_qkv_bf16(
    const unsigned short* __restrict__ xb, const unsigned short* __restrict__ wt,
    unsigned short* __restrict__ qo, unsigned short* __restrict__ ko,
    unsigned short* __restrict__ vo) {
  __shared__ unsigned short As[128 * 32];
  __shared__ unsigned short Bs[128 * 32];
  const int n0 = blockIdx.x * 128, m0 = blockIdx.y * 128;
  f32x4 acc[4][4];
#pragma unroll
  for (int i = 0; i < 4; ++i)
#pragma unroll
    for (int j = 0; j < 4; ++j) acc[i][j] = {0.f, 0.f, 0.f, 0.f};
  gemm128_core(xb, wt, As, Bs, m0, n0, 2048, acc);

  unsigned short* obase; int ldo, cb;
  if (n0 < 2048) { obase = qo; ldo = 2048; cb = n0; }
  else if (n0 < 3072) { obase = ko; ldo = 1024; cb = n0 - 2048; }
  else { obase = vo; ldo = 1024; cb = n0 - 3072; }
  const int lane = threadIdx.x & 63, wave = threadIdx.x >> 6;
  const int wm = (wave & 1) << 6, wn = (wave >> 1) << 6;
  const int rbase = m0 + wm + (lane >> 4) * 4;
  const int cbase = cb + wn + (lane & 15);
#pragma unroll
  for (int i = 0; i < 4; ++i)
#pragma unroll
    for (int j = 0; j < 4; ++j)
#pragma unroll
      for (int r = 0; r < 4; ++r)
        obase[(size_t)(rbase + i * 16 + r) * ldo + cbase + j * 16] = f2bf(acc[i][j][r]);
}

// Output projection: abuf(4096x2048 bf16) @ wot^T -> out fp32
__global__ __launch_bounds__(256) void gemm_out_bf16(
    const unsigned short* __restrict__ ab, const unsigned short* __restrict__ wot,
    float* __restrict__ out) {
  __shared__ unsigned short As[128 * 32];
  __shared__ unsigned short Bs[128 * 32];
  const int n0 = blockIdx.x * 128, m0 = blockIdx.y * 128;
  f32x4 acc[4][4];
#pragma unroll
  for (int i = 0; i < 4; ++i)
#pragma unroll
    for (int j = 0; j < 4; ++j) acc[i][j] = {0.f, 0.f, 0.f, 0.f};
  gemm128_core(ab, wot, As, Bs, m0, n0, 2048, acc);

  const int lane = threadIdx.x & 63, wave = threadIdx.x >> 6;
  const int wm = (wave & 1) << 6, wn = (wave >> 1) << 6;
  const int rbase = m0 + wm + (lane >> 4) * 4;
  const int cbase = n0 + wn + (lane & 15);
#pragma unroll
  for (int i = 0; i < 4; ++i)
#pragma unroll
    for (int j = 0; j < 4; ++j)
#pragma unroll
      for (int r = 0; r < 4; ++r)
        out[(size_t)(rbase + i * 16 + r) * 2048 + cbase + j * 16] = acc[i][j][r];
}

// ---------------------------------------------------------------------------
// RMSNorm + RoPE, in-place on bf16 rows (q: scale 1/16 folded in; k: 1.0).
// ---------------------------------------------------------------------------
__global__ __launch_bounds__(64) void rope_norm_bf16(
    unsigned short* __restrict__ qb, unsigned short* __restrict__ kb,
    const int* __restrict__ positions,
    const float* __restrict__ qns, const float* __restrict__ kns) {
  int row = blockIdx.x;
  int lane = threadIdx.x;
  unsigned short* ptr; const float* ns; float extra; int bt;
  if (row < 32768) {
    ptr = qb + (size_t)row * 256; ns = qns; extra = 0.0625f; bt = row >> 3;
  } else {
    int r = row - 32768;
    ptr = kb + (size_t)r * 256; ns = kns; extra = 1.0f; bt = r >> 2;
  }
  int pos = positions[bt];

  ushort4 u = *(const ushort4*)&ptr[lane << 2];
  float xv[4] = {bf2f(u.x), bf2f(u.y), bf2f(u.z), bf2f(u.w)};
  float ss = xv[0]*xv[0] + xv[1]*xv[1] + xv[2]*xv[2] + xv[3]*xv[3];
#pragma unroll
  for (int off = 1; off < 64; off <<= 1) ss += __shfl_xor(ss, off, 64);
  float rinv = rsqrtf(ss * (1.0f / 256.0f) + 1e-6f);

  float4 sc4 = *(const float4*)&ns[lane << 2];
  xv[0] *= rinv * (1.0f + sc4.x);
  xv[1] *= rinv * (1.0f + sc4.y);
  xv[2] *= rinv * (1.0f + sc4.z);
  xv[3] *= rinv * (1.0f + sc4.w);

  float ov[4];
#pragma unroll
  for (int c = 0; c < 4; ++c) ov[c] = __shfl_xor(xv[c], 32, 64);

  int hr = (lane & 31) << 2;
  float sgn = (lane < 32) ? -1.0f : 1.0f;
  ushort4 w;
  unsigned short res[4];
#pragma unroll
  for (int c = 0; c < 4; ++c) {
    float invts = exp2f(-(float)(hr + c) * 0.10381025296523007f);
    float angle = (float)pos * invts;
    float sn, cs;
    sincosf(angle, &sn, &cs);
    res[c] = f2bf((xv[c] * cs + sgn * ov[c] * sn) * extra);
  }
  w.x = res[0]; w.y = res[1]; w.z = res[2]; w.w = res[3];
  *(ushort4*)&ptr[lane << 2] = w;
}

// ---------------------------------------------------------------------------
// V transpose: vbf[b][t][kvh][256] -> vt[b][kvh][256][2048] (bf16)
// ---------------------------------------------------------------------------
__global__ __launch_bounds__(256) void transpose_v(
    const unsigned short* __restrict__ vbf, unsigned short* __restrict__ vt) {
  __shared__ unsigned short tile[64][68];
  int h0 = blockIdx.x * 64;
  int t0 = blockIdx.y * 64;
  int z = blockIdx.z;  // b*4 + kvh
  int tx = threadIdx.x & 15, ty = threadIdx.x >> 4;
  const unsigned short* src = vbf + ((size_t)(z >> 2) * 8192 + (z & 3)) * 256;
#pragma unroll
  for (int p = 0; p < 4; ++p) {
    ushort4 v = *(const ushort4*)&src[(size_t)(t0 + ty + 16 * p) * 1024 + h0 + tx * 4];
    tile[ty + 16 * p][tx * 4 + 0] = v.x; tile[ty + 16 * p][tx * 4 + 1] = v.y;
    tile[ty + 16 * p][tx * 4 + 2] = v.z; tile[ty + 16 * p][tx * 4 + 3] = v.w;
  }
  __syncthreads();
  unsigned short* dst = vt + (size_t)z * 256 * 2048;
#pragma unroll
  for (int p = 0; p < 4; ++p) {
    int hh = ty + 16 * p;
    ushort4 o;
    o.x = tile[tx * 4 + 0][hh]; o.y = tile[tx * 4 + 1][hh];
    o.z = tile[tx * 4 + 2][hh]; o.w = tile[tx * 4 + 3][hh];
    *(ushort4*)&dst[(size_t)(h0 + hh) * 2048 + t0 + tx * 4] = o;
  }
}

// ---------------------------------------------------------------------------
// MFMA sliding-window attention, 32x32x16 bf16, static-max softmax.
// Block = 2 waves x 32 q rows (Q-tile 64). Q & O in registers; K/V via LDS.
// l (row sums) computed by an extra ones-MFMA. O = (exp(S) V) / l.
// ---------------------------------------------------------------------------
__global__ __launch_bounds__(128, 1) void attn_mfma(
    const unsigned short* __restrict__ qb,  // [b][t][8][256]
    const unsigned short* __restrict__ kb,  // [b][t][4][256]
    const unsigned short* __restrict__ vt,  // [b][4][256][2048]
    unsigned short* __restrict__ ob) {      // [b][t][8][256]
  __shared__ __align__(16) unsigned short Kl[8192];  // [kc16][32 s][16 h]
  __shared__ __align__(16) unsigned short Vl[8192];  // [kc2][256 h][16 s]
  __shared__ __align__(16) unsigned short Ps[2048];  // [w][kc2][32 m][16 s]

  const int tid = threadIdx.x;
  const int w = tid >> 6, lane = tid & 63;
  const int l5 = lane >> 5, l31 = lane & 31;
  const int t0 = blockIdx.x * 64;
  const int n = blockIdx.y, b = blockIdx.z;
  const int kvh = n >> 1;
  const int tminw = t0 + 32 * w, tmaxw = tminw + 31;

  // Q fragments in registers (A-operand: m=l31 row, k-octet=l5)
  bf16x8 aq[16];
  {
    const unsigned short* qrow =
        qb + (((size_t)b * 2048 + tminw + l31) * 8 + n) * 256 + l5 * 8;
#pragma unroll
    for (int kc = 0; kc < 16; ++kc) aq[kc] = *(const bf16x8*)(qrow + kc * 16);
  }

  f32x16 O[8], lsum;
#pragma unroll
  for (int i = 0; i < 8; ++i)
#pragma unroll
    for (int r = 0; r < 16; ++r) O[i][r] = 0.f;
#pragma unroll
  for (int r = 0; r < 16; ++r) lsum[r] = 0.f;

  bf16x8 ones;
#pragma unroll
  for (int i = 0; i < 8; ++i) ones[i] = (short)0x3F80;  // bf16 1.0

  const unsigned short* kbase = kb + ((size_t)b * 8192 + kvh) * 256;
  const unsigned short* vbase = vt + (size_t)(b * 4 + kvh) * 256 * 2048;

  int s_lo = t0 - 1024; if (s_lo < 0) s_lo = 0;

  for (int s0 = s_lo; s0 < t0 + 64; s0 += 32) {
    __syncthreads();
    // stage K tile (32 s x 256 h -> chunked) and V tile (256 h x 32 s)
#pragma unroll
    for (int j = 0; j < 8; ++j) {
      int g = j * 128 + tid;
      int kc = g >> 6, s = (g >> 1) & 31, hi = g & 1;
      GLD16(kbase + (size_t)(s0 + s) * 1024 + kc * 16 + hi * 8,
            Kl + (j * 128 + w * 64) * 8);
    }
#pragma unroll
    for (int j = 0; j < 8; ++j) {
      int g = j * 128 + tid;
      int kc2 = g >> 9, h = (g >> 1) & 255, hi = g & 1;
      GLD16(vbase + (size_t)h * 2048 + s0 + kc2 * 16 + hi * 8,
            Vl + (j * 128 + w * 64) * 8);
    }
    __syncthreads();

    bool skip = (s0 > tmaxw) || (s0 + 31 < tminw - 1023);
    if (!skip) {
      // S = Q K^T (two parallel accumulation chains)
      f32x16 pa, pb;
#pragma unroll
      for (int r = 0; r < 16; ++r) { pa[r] = 0.f; pb[r] = 0.f; }
#pragma unroll
      for (int kc = 0; kc < 16; kc += 2) {
        bf16x8 b0 = *(const bf16x8*)&Kl[kc * 512 + l31 * 16 + l5 * 8];
        bf16x8 b1 = *(const bf16x8*)&Kl[(kc + 1) * 512 + l31 * 16 + l5 * 8];
        pa = __builtin_amdgcn_mfma_f32_32x32x16_bf16(aq[kc], b0, pa, 0, 0, 0);
        pb = __builtin_amdgcn_mfma_f32_32x32x16_bf16(aq[kc + 1], b1, pb, 0, 0, 0);
      }

      bool allvalid = (s0 + 31 <= tminw) && (s0 >= tmaxw - 1023);
      int scol = s0 + l31;
      // P = exp(S), mask -> 0; write to Ps as bf16 (A-layout)
#pragma unroll
      for (int r = 0; r < 16; ++r) {
        float sv = pa[r] + pb[r];
        float p = exp2f(sv * 1.442695040888963f);
        int m = (r & 3) + 8 * (r >> 2) + 4 * l5;
        if (!allvalid) {
          int dt = (tminw + m) - scol;
          p = (dt >= 0 && dt < 1024) ? p : 0.f;
        }
        Ps[w * 1024 + (l31 >> 4) * 512 + m * 16 + (l31 & 15)] = f2bf(p);
      }

      // PV + row-sum (wave-private Ps: no barrier needed)
      bf16x8 pf0 = *(const bf16x8*)&Ps[w * 1024 + l31 * 16 + l5 * 8];
      bf16x8 pf1 = *(const bf16x8*)&Ps[w * 1024 + 512 + l31 * 16 + l5 * 8];
      lsum = __builtin_amdgcn_mfma_f32_32x32x16_bf16(pf0, ones, lsum, 0, 0, 0);
      lsum = __builtin_amdgcn_mfma_f32_32x32x16_bf16(pf1, ones, lsum, 0, 0, 0);
#pragma unroll
      for (int hb = 0; hb < 8; ++hb) {
        bf16x8 v0 = *(const bf16x8*)&Vl[(hb * 32 + l31) * 16 + l5 * 8];
        bf16x8 v1 = *(const bf16x8*)&Vl[4096 + (hb * 32 + l31) * 16 + l5 * 8];
        O[hb] = __builtin_amdgcn_mfma_f32_32x32x16_bf16(pf0, v0, O[hb], 0, 0, 0);
        O[hb] = __builtin_amdgcn_mfma_f32_32x32x16_bf16(pf1, v1, O[hb], 0, 0, 0);
      }
    }
  }

  // epilogue: normalize and store bf16
  unsigned short* obase = ob + (((size_t)b * 2048 + tminw) * 8 + n) * 256;
#pragma unroll
  for (int r = 0; r < 16; ++r) {
    int m = (r & 3) + 8 * (r >> 2) + 4 * l5;
    float rinv = 1.0f / lsum[r];
    size_t rowoff = (size_t)m * 2048;
#pragma unroll
    for (int hb = 0; hb < 8; ++hb)
      obase[rowoff + hb * 32 + l31] = f2bf(O[hb][r] * rinv);
  }
}

extern "C" void kernel_launch(void* const* d_in, const int* in_sizes, int n_in,
                              void* d_out, int out_size, void* d_ws, size_t ws_size,
                              hipStream_t stream) {
  const float* x   = (const float*)d_in[0];
  const int* pos   = (const int*)d_in[1];
  const float* q_w = (const float*)d_in[2];
  const float* k_w = (const float*)d_in[3];
  const float* v_w = (const float*)d_in[4];
  const float* o_w = (const float*)d_in[5];
  const float* qns = (const float*)d_in[6];
  const float* kns = (const float*)d_in[7];
  float* out = (float*)d_out;

  unsigned short* W = (unsigned short*)d_ws;
  unsigned short* qb0   = W;               //  8,388,608 us  q bf16
  unsigned short* kb0   = W + 8388608;     //  4,194,304 us  k bf16
  unsigned short* vbf   = W + 12582912;    //  4,194,304 us  v bf16 (row-major)
  unsigned short* vtb   = W + 16777216;    //  4,194,304 us  v^T bf16
  unsigned short* xb    = W + 20971520;    //  8,388,608 us  x bf16
  unsigned short* wqkvt = W + 29360128;    //  8,388,608 us  qkv weights^T
  unsigned short* abuf  = wqkvt;           //  reuse after gemm_qkv
  unsigned short* wot   = W + 37748736;    //  4,194,304 us  o weights^T
  // total 41,943,040 us = 83.9 MB

  cast_bf16<<<dim3(8192), 256, 0, stream>>>(x, xb);
  transpose_wqkv<<<dim3(64, 32), 256, 0, stream>>>(q_w, k_w, v_w, wqkvt);
  gemm_qkv_bf16<<<dim3(32, 32), 256, 0, stream>>>(xb, wqkvt, qb0, kb0, vbf);
  transpose_wo<<<dim3(32, 32), 256, 0, stream>>>(o_w, wot);
  rope_norm_bf16<<<dim3(49152), 64, 0, stream>>>(qb0, kb0, pos, qns, kns);
  transpose_v<<<dim3(4, 32, 8), 256, 0, stream>>>(vbf, vtb);
  attn_mfma<<<dim3(32, 8, 2), 128, 0, stream>>>(qb0, kb0, vtb, abuf);
  gemm_out_bf16<<<dim3(16, 32), 256, 0, stream>>>(abuf, wot, out);
}

// Round 4
// 393.841 us; speedup vs baseline: 7.0849x; 1.0051x over previous
//
#include <hip/hip_runtime.h>
#include <cmath>

#define T_SEQ 2048
#define WINDOW 1024

typedef __attribute__((ext_vector_type(8))) short bf16x8;
typedef __attribute__((ext_vector_type(4))) float f32x4;
typedef __attribute__((ext_vector_type(16))) float f32x16;

__device__ __forceinline__ unsigned short f2bf(float f) {
  union { float f; unsigned int u; } v; v.f = f;
  unsigned int r = v.u + 0x7FFFu + ((v.u >> 16) & 1u);  // RNE
  return (unsigned short)(r >> 16);
}
__device__ __forceinline__ float bf2f(unsigned short u) {
  union { unsigned int i; float f; } v; v.i = ((unsigned int)u) << 16;
  return v.f;
}

#define GLD16(gp, lp)                                                  \
  __builtin_amdgcn_global_load_lds(                                    \
      (__attribute__((address_space(1))) unsigned int*)(gp),           \
      (__attribute__((address_space(3))) unsigned int*)(lp), 16, 0, 0)

// ---------------------------------------------------------------------------
// cast x (fp32) -> bf16
// ---------------------------------------------------------------------------
__global__ __launch_bounds__(256) void cast_bf16(const float* __restrict__ in,
                                                 unsigned short* __restrict__ out) {
  size_t i = (size_t)blockIdx.x * 256 + threadIdx.x;
  float4 v = *(const float4*)&in[i * 4];
  ushort4 o;
  o.x = f2bf(v.x); o.y = f2bf(v.y); o.z = f2bf(v.z); o.w = f2bf(v.w);
  *(ushort4*)&out[i * 4] = o;
}

// ---------------------------------------------------------------------------
// Bt (4096 x 2048) bf16: Bt[c][d] = w[head(c)][d][h(c)] for q|k|v cols.
// ---------------------------------------------------------------------------
__global__ __launch_bounds__(256) void transpose_wqkv(
    const float* __restrict__ qw, const float* __restrict__ kw,
    const float* __restrict__ vw, unsigned short* __restrict__ bt) {
  __shared__ float tile[64][65];
  int c0 = blockIdx.x * 64;
  int d0 = blockIdx.y * 64;
  const float* src; int hbase;
  if (c0 < 2048) { src = qw + (size_t)(c0 >> 8) * 524288; hbase = c0 & 255; }
  else if (c0 < 3072) { int cc = c0 - 2048; src = kw + (size_t)(cc >> 8) * 524288; hbase = cc & 255; }
  else { int cc = c0 - 3072; src = vw + (size_t)(cc >> 8) * 524288; hbase = cc & 255; }
  int tx = threadIdx.x & 15, ty = threadIdx.x >> 4;
#pragma unroll
  for (int p = 0; p < 4; ++p) {
    float4 v = *(const float4*)&src[(size_t)(d0 + ty + 16 * p) * 256 + hbase + tx * 4];
    tile[ty + 16 * p][tx * 4 + 0] = v.x; tile[ty + 16 * p][tx * 4 + 1] = v.y;
    tile[ty + 16 * p][tx * 4 + 2] = v.z; tile[ty + 16 * p][tx * 4 + 3] = v.w;
  }
  __syncthreads();
#pragma unroll
  for (int p = 0; p < 4; ++p) {
    int hh = ty + 16 * p;
    ushort4 o;
    o.x = f2bf(tile[tx * 4 + 0][hh]); o.y = f2bf(tile[tx * 4 + 1][hh]);
    o.z = f2bf(tile[tx * 4 + 2][hh]); o.w = f2bf(tile[tx * 4 + 3][hh]);
    *(ushort4*)&bt[(size_t)(c0 + hh) * 2048 + d0 + tx * 4] = o;
  }
}

// ---------------------------------------------------------------------------
// wot (2048 x 2048) bf16: wot[d][j] = o_w[j][d]  (j = n*256+h)
// ---------------------------------------------------------------------------
__global__ __launch_bounds__(256) void transpose_wo(
    const float* __restrict__ ow, unsigned short* __restrict__ wot) {
  __shared__ float tile[64][65];
  int j0 = blockIdx.x * 64;
  int d0 = blockIdx.y * 64;
  int tx = threadIdx.x & 15, ty = threadIdx.x >> 4;
#pragma unroll
  for (int p = 0; p < 4; ++p) {
    float4 v = *(const float4*)&ow[(size_t)(j0 + ty + 16 * p) * 2048 + d0 + tx * 4];
    tile[ty + 16 * p][tx * 4 + 0] = v.x; tile[ty + 16 * p][tx * 4 + 1] = v.y;
    tile[ty + 16 * p][tx * 4 + 2] = v.z; tile[ty + 16 * p][tx * 4 + 3] = v.w;
  }
  __syncthreads();
#pragma unroll
  for (int p = 0; p < 4; ++p) {
    int hh = ty + 16 * p;
    ushort4 o;
    o.x = f2bf(tile[tx * 4 + 0][hh]); o.y = f2bf(tile[tx * 4 + 1][hh]);
    o.z = f2bf(tile[tx * 4 + 2][hh]); o.w = f2bf(tile[tx * 4 + 3][hh]);
    *(ushort4*)&wot[(size_t)(d0 + hh) * 2048 + j0 + tx * 4] = o;
  }
}

// ---------------------------------------------------------------------------
// m97-style bf16 MFMA GEMM core (16x16x32), 128x128 tile.
// ---------------------------------------------------------------------------
__device__ __forceinline__ void gemm128_core(
    const unsigned short* __restrict__ A, const unsigned short* __restrict__ Bt,
    unsigned short* As, unsigned short* Bs, int m0, int n0, int K,
    f32x4 acc[4][4]) {
  const int tid = threadIdx.x;
  const int wave = tid >> 6, lane = tid & 63;
  const int wm = (wave & 1) << 6, wn = (wave >> 1) << 6;
  const int i0 = wave * 2, i1 = wave * 2 + 1;
  const int sr = lane >> 2;
  const int sc = (lane & 3) * 8;
  const size_t ar0 = (size_t)(m0 + i0 * 16 + sr) * K + sc;
  const size_t ar1 = (size_t)(m0 + i1 * 16 + sr) * K + sc;
  const size_t br0 = (size_t)(n0 + i0 * 16 + sr) * K + sc;
  const size_t br1 = (size_t)(n0 + i1 * 16 + sr) * K + sc;
  const int fm = lane & 15, fk = (lane >> 4) * 8;

  for (int kt = 0; kt < K; kt += 32) {
    GLD16(A + ar0 + kt, As + i0 * 512);
    GLD16(A + ar1 + kt, As + i1 * 512);
    GLD16(Bt + br0 + kt, Bs + i0 * 512);
    GLD16(Bt + br1 + kt, Bs + i1 * 512);
    __syncthreads();
    bf16x8 af[4], bv[4];
#pragma unroll
    for (int i = 0; i < 4; ++i)
      af[i] = *(const bf16x8*)&As[(wm + i * 16 + fm) * 32 + fk];
#pragma unroll
    for (int j = 0; j < 4; ++j)
      bv[j] = *(const bf16x8*)&Bs[(wn + j * 16 + fm) * 32 + fk];
#pragma unroll
    for (int i = 0; i < 4; ++i)
#pragma unroll
      for (int j = 0; j < 4; ++j)
        acc[i][j] = __builtin_amdgcn_mfma_f32_16x16x32_bf16(af[i], bv[j], acc[i][j], 0, 0, 0);
    __syncthreads();
  }
}

// QKV projection -> bf16 outputs qb0[b][t][8][256], kb0[b][t][4][256], vbf[b][t][4][256]
__global__ __launch_bounds__(256) void gemm_qkv_bf16(
    const unsigned short* __restrict__ xb, const unsigned short* __restrict__ wt,
    unsigned short* __restrict__ qo, unsigned short* __restrict__ ko,
    unsigned short* __restrict__ vo) {
  __shared__ unsigned short As[128 * 32];
  __shared__ unsigned short Bs[128 * 32];
  const int n0 = blockIdx.x * 128, m0 = blockIdx.y * 128;
  f32x4 acc[4][4];
#pragma unroll
  for (int i = 0; i < 4; ++i)
#pragma unroll
    for (int j = 0; j < 4; ++j) acc[i][j] = {0.f, 0.f, 0.f, 0.f};
  gemm128_core(xb, wt, As, Bs, m0, n0, 2048, acc);

  unsigned short* obase; int ldo, cb;
  if (n0 < 2048) { obase = qo; ldo = 2048; cb = n0; }
  else if (n0 < 3072) { obase = ko; ldo = 1024; cb = n0 - 2048; }
  else { obase = vo; ldo = 1024; cb = n0 - 3072; }
  const int lane = threadIdx.x & 63, wave = threadIdx.x >> 6;
  const int wm = (wave & 1) << 6, wn = (wave >> 1) << 6;
  const int rbase = m0 + wm + (lane >> 4) * 4;
  const int cbase = cb + wn + (lane & 15);
#pragma unroll
  for (int i = 0; i < 4; ++i)
#pragma unroll
    for (int j = 0; j < 4; ++j)
#pragma unroll
      for (int r = 0; r < 4; ++r)
        obase[(size_t)(rbase + i * 16 + r) * ldo + cbase + j * 16] = f2bf(acc[i][j][r]);
}

// Output projection: abuf(4096x2048 bf16) @ wot^T -> out fp32
__global__ __launch_bounds__(256) void gemm_out_bf16(
    const unsigned short* __restrict__ ab, const unsigned short* __restrict__ wot,
    float* __restrict__ out) {
  __shared__ unsigned short As[128 * 32];
  __shared__ unsigned short Bs[128 * 32];
  const int n0 = blockIdx.x * 128, m0 = blockIdx.y * 128;
  f32x4 acc[4][4];
#pragma unroll
  for (int i = 0; i < 4; ++i)
#pragma unroll
    for (int j = 0; j < 4; ++j) acc[i][j] = {0.f, 0.f, 0.f, 0.f};
  gemm128_core(ab, wot, As, Bs, m0, n0, 2048, acc);

  const int lane = threadIdx.x & 63, wave = threadIdx.x >> 6;
  const int wm = (wave & 1) << 6, wn = (wave >> 1) << 6;
  const int rbase = m0 + wm + (lane >> 4) * 4;
  const int cbase = n0 + wn + (lane & 15);
#pragma unroll
  for (int i = 0; i < 4; ++i)
#pragma unroll
    for (int j = 0; j < 4; ++j)
#pragma unroll
      for (int r = 0; r < 4; ++r)
        out[(size_t)(rbase + i * 16 + r) * 2048 + cbase + j * 16] = acc[i][j][r];
}

// ---------------------------------------------------------------------------
// RMSNorm + RoPE, in-place on bf16 rows (q: scale 1/16 folded in; k: 1.0).
// ---------------------------------------------------------------------------
__global__ __launch_bounds__(64) void rope_norm_bf16(
    unsigned short* __restrict__ qb, unsigned short* __restrict__ kb,
    const int* __restrict__ positions,
    const float* __restrict__ qns, const float* __restrict__ kns) {
  int row = blockIdx.x;
  int lane = threadIdx.x;
  unsigned short* ptr; const float* ns; float extra; int bt;
  if (row < 32768) {
    ptr = qb + (size_t)row * 256; ns = qns; extra = 0.0625f; bt = row >> 3;
  } else {
    int r = row - 32768;
    ptr = kb + (size_t)r * 256; ns = kns; extra = 1.0f; bt = r >> 2;
  }
  int pos = positions[bt];

  ushort4 u = *(const ushort4*)&ptr[lane << 2];
  float xv[4] = {bf2f(u.x), bf2f(u.y), bf2f(u.z), bf2f(u.w)};
  float ss = xv[0]*xv[0] + xv[1]*xv[1] + xv[2]*xv[2] + xv[3]*xv[3];
#pragma unroll
  for (int off = 1; off < 64; off <<= 1) ss += __shfl_xor(ss, off, 64);
  float rinv = rsqrtf(ss * (1.0f / 256.0f) + 1e-6f);

  float4 sc4 = *(const float4*)&ns[lane << 2];
  xv[0] *= rinv * (1.0f + sc4.x);
  xv[1] *= rinv * (1.0f + sc4.y);
  xv[2] *= rinv * (1.0f + sc4.z);
  xv[3] *= rinv * (1.0f + sc4.w);

  float ov[4];
#pragma unroll
  for (int c = 0; c < 4; ++c) ov[c] = __shfl_xor(xv[c], 32, 64);

  int hr = (lane & 31) << 2;
  float sgn = (lane < 32) ? -1.0f : 1.0f;
  ushort4 w;
  unsigned short res[4];
#pragma unroll
  for (int c = 0; c < 4; ++c) {
    float invts = exp2f(-(float)(hr + c) * 0.10381025296523007f);
    float angle = (float)pos * invts;
    float sn, cs;
    __sincosf(angle, &sn, &cs);
    res[c] = f2bf((xv[c] * cs + sgn * ov[c] * sn) * extra);
  }
  w.x = res[0]; w.y = res[1]; w.z = res[2]; w.w = res[3];
  *(ushort4*)&ptr[lane << 2] = w;
}

// ---------------------------------------------------------------------------
// V transpose: vbf[b][t][kvh][256] -> vt[b][kvh][256][2048] (bf16)
// ---------------------------------------------------------------------------
__global__ __launch_bounds__(256) void transpose_v(
    const unsigned short* __restrict__ vbf, unsigned short* __restrict__ vt) {
  __shared__ unsigned short tile[64][68];
  int h0 = blockIdx.x * 64;
  int t0 = blockIdx.y * 64;
  int z = blockIdx.z;  // b*4 + kvh
  int tx = threadIdx.x & 15, ty = threadIdx.x >> 4;
  const unsigned short* src = vbf + ((size_t)(z >> 2) * 8192 + (z & 3)) * 256;
#pragma unroll
  for (int p = 0; p < 4; ++p) {
    ushort4 v = *(const ushort4*)&src[(size_t)(t0 + ty + 16 * p) * 1024 + h0 + tx * 4];
    tile[ty + 16 * p][tx * 4 + 0] = v.x; tile[ty + 16 * p][tx * 4 + 1] = v.y;
    tile[ty + 16 * p][tx * 4 + 2] = v.z; tile[ty + 16 * p][tx * 4 + 3] = v.w;
  }
  __syncthreads();
  unsigned short* dst = vt + (size_t)z * 256 * 2048;
#pragma unroll
  for (int p = 0; p < 4; ++p) {
    int hh = ty + 16 * p;
    ushort4 o;
    o.x = tile[tx * 4 + 0][hh]; o.y = tile[tx * 4 + 1][hh];
    o.z = tile[tx * 4 + 2][hh]; o.w = tile[tx * 4 + 3][hh];
    *(ushort4*)&dst[(size_t)(h0 + hh) * 2048 + t0 + tx * 4] = o;
  }
}

// ---------------------------------------------------------------------------
// MFMA sliding-window attention, 32x32x16 bf16, static-max softmax.
// Block = 256 thr = 4 waves: wave w -> head 2*kvh + (w>>1), rows t0+32*(w&1).
// K/V staged once per block, consumed by all 4 waves (GQA sharing).
// Double-buffered LDS; prefetch issued right after barrier, covered by MFMA.
// ---------------------------------------------------------------------------
__global__ __launch_bounds__(256, 1) void attn_mfma(
    const unsigned short* __restrict__ qb,  // [b][t][8][256]
    const unsigned short* __restrict__ kb,  // [b][t][4][256]
    const unsigned short* __restrict__ vt,  // [b][4][256][2048]
    unsigned short* __restrict__ ob) {      // [b][t][8][256]
  __shared__ __align__(16) unsigned short Kl[16384];  // 2 bufs x [kc16][32 s][16 h]
  __shared__ __align__(16) unsigned short Vl[16384];  // 2 bufs x [kc2][256 h][16 s]
  __shared__ __align__(16) unsigned short Ps[4096];   // [w][kc2][32 m][16 s]

  const int tid = threadIdx.x;
  const int w = tid >> 6, lane = tid & 63;
  const int l5 = lane >> 5, l31 = lane & 31;
  const int t0 = blockIdx.x * 64;
  const int kvh = blockIdx.y, b = blockIdx.z;
  const int n = 2 * kvh + (w >> 1);
  const int tminw = t0 + 32 * (w & 1), tmaxw = tminw + 31;

  // Q fragments in registers (A-operand: m=l31 row, k-octet=l5)
  bf16x8 aq[16];
  {
    const unsigned short* qrow =
        qb + (((size_t)b * 2048 + tminw + l31) * 8 + n) * 256 + l5 * 8;
#pragma unroll
    for (int kc = 0; kc < 16; ++kc) aq[kc] = *(const bf16x8*)(qrow + kc * 16);
  }

  f32x16 O[8], lsum;
#pragma unroll
  for (int i = 0; i < 8; ++i)
#pragma unroll
    for (int r = 0; r < 16; ++r) O[i][r] = 0.f;
#pragma unroll
  for (int r = 0; r < 16; ++r) lsum[r] = 0.f;

  bf16x8 ones;
#pragma unroll
  for (int i = 0; i < 8; ++i) ones[i] = (short)0x3F80;  // bf16 1.0

  const unsigned short* kbase = kb + ((size_t)b * 8192 + kvh) * 256;
  const unsigned short* vbase = vt + (size_t)(b * 4 + kvh) * 256 * 2048;

  int s_lo = t0 - 1024; if (s_lo < 0) s_lo = 0;
  const int s_end = t0 + 64;

  // staging: 4 GLD16/wave for K, 4 for V. identity mapping g -> lds elem g*8.
#define STAGE(buf, s0)                                                        \
  {                                                                           \
    _Pragma("unroll") for (int j = 0; j < 4; ++j) {                           \
      int g = j * 256 + tid;                                                  \
      int kc = g >> 6, s = (g >> 1) & 31, hi = g & 1;                         \
      GLD16(kbase + (size_t)((s0) + s) * 1024 + kc * 16 + hi * 8,             \
            Kl + (buf) * 8192 + (j * 256 + w * 64) * 8);                      \
    }                                                                         \
    _Pragma("unroll") for (int j = 0; j < 4; ++j) {                           \
      int g = j * 256 + tid;                                                  \
      int kc2 = g >> 9, h = (g >> 1) & 255, hi = g & 1;                       \
      GLD16(vbase + (size_t)h * 2048 + (s0) + kc2 * 16 + hi * 8,              \
            Vl + (buf) * 8192 + (j * 256 + w * 64) * 8);                      \
    }                                                                         \
  }

  STAGE(0, s_lo);
  int buf = 0;

  for (int s0 = s_lo; s0 < s_end; s0 += 32, buf ^= 1) {
    __syncthreads();  // drains current buf's staging; all waves done with buf^1
    int s1 = s0 + 32;
    if (s1 < s_end) STAGE(buf ^ 1, s1);  // in flight during compute below

    bool skip = (s0 > tmaxw) || (s0 + 31 < tminw - 1023);
    if (!skip) {
      const unsigned short* Kb = Kl + buf * 8192;
      const unsigned short* Vb = Vl + buf * 8192;
      // S = Q K^T (two parallel accumulation chains)
      f32x16 pa, pb;
#pragma unroll
      for (int r = 0; r < 16; ++r) { pa[r] = 0.f; pb[r] = 0.f; }
#pragma unroll
      for (int kc = 0; kc < 16; kc += 2) {
        bf16x8 b0 = *(const bf16x8*)&Kb[kc * 512 + l31 * 16 + l5 * 8];
        bf16x8 b1 = *(const bf16x8*)&Kb[(kc + 1) * 512 + l31 * 16 + l5 * 8];
        pa = __builtin_amdgcn_mfma_f32_32x32x16_bf16(aq[kc], b0, pa, 0, 0, 0);
        pb = __builtin_amdgcn_mfma_f32_32x32x16_bf16(aq[kc + 1], b1, pb, 0, 0, 0);
      }

      bool allvalid = (s0 + 31 <= tminw) && (s0 >= tmaxw - 1023);
      int scol = s0 + l31;
      // P = exp(S), mask -> 0; write to Ps as bf16 (A-layout, wave-private)
#pragma unroll
      for (int r = 0; r < 16; ++r) {
        float sv = pa[r] + pb[r];
        float p = exp2f(sv * 1.442695040888963f);
        int m = (r & 3) + 8 * (r >> 2) + 4 * l5;
        if (!allvalid) {
          int dt = (tminw + m) - scol;
          p = (dt >= 0 && dt < 1024) ? p : 0.f;
        }
        Ps[w * 1024 + (l31 >> 4) * 512 + m * 16 + (l31 & 15)] = f2bf(p);
      }

      // PV + row-sum (wave-private Ps: no barrier needed)
      bf16x8 pf0 = *(const bf16x8*)&Ps[w * 1024 + l31 * 16 + l5 * 8];
      bf16x8 pf1 = *(const bf16x8*)&Ps[w * 1024 + 512 + l31 * 16 + l5 * 8];
      lsum = __builtin_amdgcn_mfma_f32_32x32x16_bf16(pf0, ones, lsum, 0, 0, 0);
      lsum = __builtin_amdgcn_mfma_f32_32x32x16_bf16(pf1, ones, lsum, 0, 0, 0);
#pragma unroll
      for (int hb = 0; hb < 8; ++hb) {
        bf16x8 v0 = *(const bf16x8*)&Vb[(hb * 32 + l31) * 16 + l5 * 8];
        bf16x8 v1 = *(const bf16x8*)&Vb[4096 + (hb * 32 + l31) * 16 + l5 * 8];
        O[hb] = __builtin_amdgcn_mfma_f32_32x32x16_bf16(pf0, v0, O[hb], 0, 0, 0);
        O[hb] = __builtin_amdgcn_mfma_f32_32x32x16_bf16(pf1, v1, O[hb], 0, 0, 0);
      }
    }
  }

  // epilogue: normalize and store bf16
  unsigned short* obase = ob + (((size_t)b * 2048 + tminw) * 8 + n) * 256;
#pragma unroll
  for (int r = 0; r < 16; ++r) {
    int m = (r & 3) + 8 * (r >> 2) + 4 * l5;
    float rinv = 1.0f / lsum[r];
    size_t rowoff = (size_t)m * 2048;
#pragma unroll
    for (int hb = 0; hb < 8; ++hb)
      obase[rowoff + hb * 32 + l31] = f2bf(O[hb][r] * rinv);
  }
}

extern "C" void kernel_launch(void* const* d_in, const int* in_sizes, int n_in,
                              void* d_out, int out_size, void* d_ws, size_t ws_size,
                              hipStream_t stream) {
  const float* x   = (const float*)d_in[0];
  const int* pos   = (const int*)d_in[1];
  const float* q_w = (const float*)d_in[2];
  const float* k_w = (const float*)d_in[3];
  const float* v_w = (const float*)d_in[4];
  const float* o_w = (const float*)d_in[5];
  const float* qns = (const float*)d_in[6];
  const float* kns = (const float*)d_in[7];
  float* out = (float*)d_out;

  unsigned short* W = (unsigned short*)d_ws;
  unsigned short* qb0   = W;               //  8,388,608 us  q bf16
  unsigned short* kb0   = W + 8388608;     //  4,194,304 us  k bf16
  unsigned short* vbf   = W + 12582912;    //  4,194,304 us  v bf16 (row-major)
  unsigned short* vtb   = W + 16777216;    //  4,194,304 us  v^T bf16
  unsigned short* xb    = W + 20971520;    //  8,388,608 us  x bf16
  unsigned short* wqkvt = W + 29360128;    //  8,388,608 us  qkv weights^T
  unsigned short* abuf  = wqkvt;           //  reuse after gemm_qkv
  unsigned short* wot   = W + 37748736;    //  4,194,304 us  o weights^T
  // total 41,943,040 us = 83.9 MB

  cast_bf16<<<dim3(8192), 256, 0, stream>>>(x, xb);
  transpose_wqkv<<<dim3(64, 32), 256, 0, stream>>>(q_w, k_w, v_w, wqkvt);
  gemm_qkv_bf16<<<dim3(32, 32), 256, 0, stream>>>(xb, wqkvt, qb0, kb0, vbf);
  transpose_wo<<<dim3(32, 32), 256, 0, stream>>>(o_w, wot);
  rope_norm_bf16<<<dim3(49152), 64, 0, stream>>>(qb0, kb0, pos, qns, kns);
  transpose_v<<<dim3(4, 32, 8), 256, 0, stream>>>(vbf, vtb);
  attn_mfma<<<dim3(32, 4, 2), 256, 0, stream>>>(qb0, kb0, vtb, abuf);
  gemm_out_bf16<<<dim3(16, 32), 256, 0, stream>>>(abuf, wot, out);
}

// Round 5
// 387.340 us; speedup vs baseline: 7.2038x; 1.0168x over previous
//
#include <hip/hip_runtime.h>
#include <cmath>

#define T_SEQ 2048
#define WINDOW 1024

typedef __attribute__((ext_vector_type(8))) short bf16x8;
typedef __attribute__((ext_vector_type(4))) float f32x4;
typedef __attribute__((ext_vector_type(16))) float f32x16;

__device__ __forceinline__ unsigned short f2bf(float f) {
  union { float f; unsigned int u; } v; v.f = f;
  unsigned int r = v.u + 0x7FFFu + ((v.u >> 16) & 1u);  // RNE
  return (unsigned short)(r >> 16);
}
__device__ __forceinline__ float bf2f(unsigned short u) {
  union { unsigned int i; float f; } v; v.i = ((unsigned int)u) << 16;
  return v.f;
}

#define GLD16(gp, lp)                                                  \
  __builtin_amdgcn_global_load_lds(                                    \
      (__attribute__((address_space(1))) unsigned int*)(gp),           \
      (__attribute__((address_space(3))) unsigned int*)(lp), 16, 0, 0)

// ---------------------------------------------------------------------------
// cast x (fp32) -> bf16
// ---------------------------------------------------------------------------
__global__ __launch_bounds__(256) void cast_bf16(const float* __restrict__ in,
                                                 unsigned short* __restrict__ out) {
  size_t i = (size_t)blockIdx.x * 256 + threadIdx.x;
  float4 v = *(const float4*)&in[i * 4];
  ushort4 o;
  o.x = f2bf(v.x); o.y = f2bf(v.y); o.z = f2bf(v.z); o.w = f2bf(v.w);
  *(ushort4*)&out[i * 4] = o;
}

// ---------------------------------------------------------------------------
// Bt (4096 x 2048) bf16: Bt[c][d] = w[head(c)][d][h(c)] for q|k|v cols.
// ---------------------------------------------------------------------------
__global__ __launch_bounds__(256) void transpose_wqkv(
    const float* __restrict__ qw, const float* __restrict__ kw,
    const float* __restrict__ vw, unsigned short* __restrict__ bt) {
  __shared__ float tile[64][65];
  int c0 = blockIdx.x * 64;
  int d0 = blockIdx.y * 64;
  const float* src; int hbase;
  if (c0 < 2048) { src = qw + (size_t)(c0 >> 8) * 524288; hbase = c0 & 255; }
  else if (c0 < 3072) { int cc = c0 - 2048; src = kw + (size_t)(cc >> 8) * 524288; hbase = cc & 255; }
  else { int cc = c0 - 3072; src = vw + (size_t)(cc >> 8) * 524288; hbase = cc & 255; }
  int tx = threadIdx.x & 15, ty = threadIdx.x >> 4;
#pragma unroll
  for (int p = 0; p < 4; ++p) {
    float4 v = *(const float4*)&src[(size_t)(d0 + ty + 16 * p) * 256 + hbase + tx * 4];
    tile[ty + 16 * p][tx * 4 + 0] = v.x; tile[ty + 16 * p][tx * 4 + 1] = v.y;
    tile[ty + 16 * p][tx * 4 + 2] = v.z; tile[ty + 16 * p][tx * 4 + 3] = v.w;
  }
  __syncthreads();
#pragma unroll
  for (int p = 0; p < 4; ++p) {
    int hh = ty + 16 * p;
    ushort4 o;
    o.x = f2bf(tile[tx * 4 + 0][hh]); o.y = f2bf(tile[tx * 4 + 1][hh]);
    o.z = f2bf(tile[tx * 4 + 2][hh]); o.w = f2bf(tile[tx * 4 + 3][hh]);
    *(ushort4*)&bt[(size_t)(c0 + hh) * 2048 + d0 + tx * 4] = o;
  }
}

// ---------------------------------------------------------------------------
// wot (2048 x 2048) bf16: wot[d][j] = o_w[j][d]  (j = n*256+h)
// ---------------------------------------------------------------------------
__global__ __launch_bounds__(256) void transpose_wo(
    const float* __restrict__ ow, unsigned short* __restrict__ wot) {
  __shared__ float tile[64][65];
  int j0 = blockIdx.x * 64;
  int d0 = blockIdx.y * 64;
  int tx = threadIdx.x & 15, ty = threadIdx.x >> 4;
#pragma unroll
  for (int p = 0; p < 4; ++p) {
    float4 v = *(const float4*)&ow[(size_t)(j0 + ty + 16 * p) * 2048 + d0 + tx * 4];
    tile[ty + 16 * p][tx * 4 + 0] = v.x; tile[ty + 16 * p][tx * 4 + 1] = v.y;
    tile[ty + 16 * p][tx * 4 + 2] = v.z; tile[ty + 16 * p][tx * 4 + 3] = v.w;
  }
  __syncthreads();
#pragma unroll
  for (int p = 0; p < 4; ++p) {
    int hh = ty + 16 * p;
    ushort4 o;
    o.x = f2bf(tile[tx * 4 + 0][hh]); o.y = f2bf(tile[tx * 4 + 1][hh]);
    o.z = f2bf(tile[tx * 4 + 2][hh]); o.w = f2bf(tile[tx * 4 + 3][hh]);
    *(ushort4*)&wot[(size_t)(d0 + hh) * 2048 + j0 + tx * 4] = o;
  }
}

// ---------------------------------------------------------------------------
// m97-style bf16 MFMA GEMM core (16x16x32), 128x128 tile.
// ---------------------------------------------------------------------------
__device__ __forceinline__ void gemm128_core(
    const unsigned short* __restrict__ A, const unsigned short* __restrict__ Bt,
    unsigned short* As, unsigned short* Bs, int m0, int n0, int K,
    f32x4 acc[4][4]) {
  const int tid = threadIdx.x;
  const int wave = tid >> 6, lane = tid & 63;
  const int wm = (wave & 1) << 6, wn = (wave >> 1) << 6;
  const int i0 = wave * 2, i1 = wave * 2 + 1;
  const int sr = lane >> 2;
  const int sc = (lane & 3) * 8;
  const size_t ar0 = (size_t)(m0 + i0 * 16 + sr) * K + sc;
  const size_t ar1 = (size_t)(m0 + i1 * 16 + sr) * K + sc;
  const size_t br0 = (size_t)(n0 + i0 * 16 + sr) * K + sc;
  const size_t br1 = (size_t)(n0 + i1 * 16 + sr) * K + sc;
  const int fm = lane & 15, fk = (lane >> 4) * 8;

  for (int kt = 0; kt < K; kt += 32) {
    GLD16(A + ar0 + kt, As + i0 * 512);
    GLD16(A + ar1 + kt, As + i1 * 512);
    GLD16(Bt + br0 + kt, Bs + i0 * 512);
    GLD16(Bt + br1 + kt, Bs + i1 * 512);
    __syncthreads();
    bf16x8 af[4], bv[4];
#pragma unroll
    for (int i = 0; i < 4; ++i)
      af[i] = *(const bf16x8*)&As[(wm + i * 16 + fm) * 32 + fk];
#pragma unroll
    for (int j = 0; j < 4; ++j)
      bv[j] = *(const bf16x8*)&Bs[(wn + j * 16 + fm) * 32 + fk];
#pragma unroll
    for (int i = 0; i < 4; ++i)
#pragma unroll
      for (int j = 0; j < 4; ++j)
        acc[i][j] = __builtin_amdgcn_mfma_f32_16x16x32_bf16(af[i], bv[j], acc[i][j], 0, 0, 0);
    __syncthreads();
  }
}

// QKV projection -> bf16 outputs qb0[b][t][8][256], kb0[b][t][4][256], vbf[b][t][4][256]
__global__ __launch_bounds__(256) void gemm_qkv_bf16(
    const unsigned short* __restrict__ xb, const unsigned short* __restrict__ wt,
    unsigned short* __restrict__ qo, unsigned short* __restrict__ ko,
    unsigned short* __restrict__ vo) {
  __shared__ unsigned short As[128 * 32];
  __shared__ unsigned short Bs[128 * 32];
  const int n0 = blockIdx.x * 128, m0 = blockIdx.y * 128;
  f32x4 acc[4][4];
#pragma unroll
  for (int i = 0; i < 4; ++i)
#pragma unroll
    for (int j = 0; j < 4; ++j) acc[i][j] = {0.f, 0.f, 0.f, 0.f};
  gemm128_core(xb, wt, As, Bs, m0, n0, 2048, acc);

  unsigned short* obase; int ldo, cb;
  if (n0 < 2048) { obase = qo; ldo = 2048; cb = n0; }
  else if (n0 < 3072) { obase = ko; ldo = 1024; cb = n0 - 2048; }
  else { obase = vo; ldo = 1024; cb = n0 - 3072; }
  const int lane = threadIdx.x & 63, wave = threadIdx.x >> 6;
  const int wm = (wave & 1) << 6, wn = (wave >> 1) << 6;
  const int rbase = m0 + wm + (lane >> 4) * 4;
  const int cbase = cb + wn + (lane & 15);
#pragma unroll
  for (int i = 0; i < 4; ++i)
#pragma unroll
    for (int j = 0; j < 4; ++j)
#pragma unroll
      for (int r = 0; r < 4; ++r)
        obase[(size_t)(rbase + i * 16 + r) * ldo + cbase + j * 16] = f2bf(acc[i][j][r]);
}

// Output projection: abuf(4096x2048 bf16) @ wot^T -> out fp32
__global__ __launch_bounds__(256) void gemm_out_bf16(
    const unsigned short* __restrict__ ab, const unsigned short* __restrict__ wot,
    float* __restrict__ out) {
  __shared__ unsigned short As[128 * 32];
  __shared__ unsigned short Bs[128 * 32];
  const int n0 = blockIdx.x * 128, m0 = blockIdx.y * 128;
  f32x4 acc[4][4];
#pragma unroll
  for (int i = 0; i < 4; ++i)
#pragma unroll
    for (int j = 0; j < 4; ++j) acc[i][j] = {0.f, 0.f, 0.f, 0.f};
  gemm128_core(ab, wot, As, Bs, m0, n0, 2048, acc);

  const int lane = threadIdx.x & 63, wave = threadIdx.x >> 6;
  const int wm = (wave & 1) << 6, wn = (wave >> 1) << 6;
  const int rbase = m0 + wm + (lane >> 4) * 4;
  const int cbase = n0 + wn + (lane & 15);
#pragma unroll
  for (int i = 0; i < 4; ++i)
#pragma unroll
    for (int j = 0; j < 4; ++j)
#pragma unroll
      for (int r = 0; r < 4; ++r)
        out[(size_t)(rbase + i * 16 + r) * 2048 + cbase + j * 16] = acc[i][j][r];
}

// ---------------------------------------------------------------------------
// RMSNorm + RoPE, in-place on bf16 rows (q: scale 1/16 folded in; k: 1.0).
// ---------------------------------------------------------------------------
__global__ __launch_bounds__(64) void rope_norm_bf16(
    unsigned short* __restrict__ qb, unsigned short* __restrict__ kb,
    const int* __restrict__ positions,
    const float* __restrict__ qns, const float* __restrict__ kns) {
  int row = blockIdx.x;
  int lane = threadIdx.x;
  unsigned short* ptr; const float* ns; float extra; int bt;
  if (row < 32768) {
    ptr = qb + (size_t)row * 256; ns = qns; extra = 0.0625f; bt = row >> 3;
  } else {
    int r = row - 32768;
    ptr = kb + (size_t)r * 256; ns = kns; extra = 1.0f; bt = r >> 2;
  }
  int pos = positions[bt];

  ushort4 u = *(const ushort4*)&ptr[lane << 2];
  float xv[4] = {bf2f(u.x), bf2f(u.y), bf2f(u.z), bf2f(u.w)};
  float ss = xv[0]*xv[0] + xv[1]*xv[1] + xv[2]*xv[2] + xv[3]*xv[3];
#pragma unroll
  for (int off = 1; off < 64; off <<= 1) ss += __shfl_xor(ss, off, 64);
  float rinv = rsqrtf(ss * (1.0f / 256.0f) + 1e-6f);

  float4 sc4 = *(const float4*)&ns[lane << 2];
  xv[0] *= rinv * (1.0f + sc4.x);
  xv[1] *= rinv * (1.0f + sc4.y);
  xv[2] *= rinv * (1.0f + sc4.z);
  xv[3] *= rinv * (1.0f + sc4.w);

  float ov[4];
#pragma unroll
  for (int c = 0; c < 4; ++c) ov[c] = __shfl_xor(xv[c], 32, 64);

  int hr = (lane & 31) << 2;
  float sgn = (lane < 32) ? -1.0f : 1.0f;
  ushort4 w;
  unsigned short res[4];
#pragma unroll
  for (int c = 0; c < 4; ++c) {
    float invts = exp2f(-(float)(hr + c) * 0.10381025296523007f);
    float angle = (float)pos * invts;
    float sn, cs;
    __sincosf(angle, &sn, &cs);
    res[c] = f2bf((xv[c] * cs + sgn * ov[c] * sn) * extra);
  }
  w.x = res[0]; w.y = res[1]; w.z = res[2]; w.w = res[3];
  *(ushort4*)&ptr[lane << 2] = w;
}

// ---------------------------------------------------------------------------
// V transpose: vbf[b][t][kvh][256] -> vt[b][kvh][256][2048] (bf16)
// ---------------------------------------------------------------------------
__global__ __launch_bounds__(256) void transpose_v(
    const unsigned short* __restrict__ vbf, unsigned short* __restrict__ vt) {
  __shared__ unsigned short tile[64][68];
  int h0 = blockIdx.x * 64;
  int t0 = blockIdx.y * 64;
  int z = blockIdx.z;  // b*4 + kvh
  int tx = threadIdx.x & 15, ty = threadIdx.x >> 4;
  const unsigned short* src = vbf + ((size_t)(z >> 2) * 8192 + (z & 3)) * 256;
#pragma unroll
  for (int p = 0; p < 4; ++p) {
    ushort4 v = *(const ushort4*)&src[(size_t)(t0 + ty + 16 * p) * 1024 + h0 + tx * 4];
    tile[ty + 16 * p][tx * 4 + 0] = v.x; tile[ty + 16 * p][tx * 4 + 1] = v.y;
    tile[ty + 16 * p][tx * 4 + 2] = v.z; tile[ty + 16 * p][tx * 4 + 3] = v.w;
  }
  __syncthreads();
  unsigned short* dst = vt + (size_t)z * 256 * 2048;
#pragma unroll
  for (int p = 0; p < 4; ++p) {
    int hh = ty + 16 * p;
    ushort4 o;
    o.x = tile[tx * 4 + 0][hh]; o.y = tile[tx * 4 + 1][hh];
    o.z = tile[tx * 4 + 2][hh]; o.w = tile[tx * 4 + 3][hh];
    *(ushort4*)&dst[(size_t)(h0 + hh) * 2048 + t0 + tx * 4] = o;
  }
}

// ---------------------------------------------------------------------------
// MFMA sliding-window attention, 32x32x16 bf16, static-max softmax.
// Block = 256 thr = 4 waves: wave w -> head 2*kvh + (w>>1), rows t0+32*(w&1).
// K/V staged once per block (single buffer), consumed by all 4 waves (GQA).
// XCD swizzle: blockIdx.x & 7 = (kvh,b) pair -> all 32 t-blocks of one
// (b,kvh) land on one XCD (round-robin dispatch), K/V (2 MB) stays in its L2.
// ---------------------------------------------------------------------------
__global__ __launch_bounds__(256, 1) void attn_mfma(
    const unsigned short* __restrict__ qb,  // [b][t][8][256]
    const unsigned short* __restrict__ kb,  // [b][t][4][256]
    const unsigned short* __restrict__ vt,  // [b][4][256][2048]
    unsigned short* __restrict__ ob) {      // [b][t][8][256]
  __shared__ __align__(16) unsigned short Kl[8192];   // [kc16][32 s][16 h]
  __shared__ __align__(16) unsigned short Vl[8192];   // [kc2][256 h][16 s]
  __shared__ __align__(16) unsigned short Ps[4096];   // [w][kc2][32 m][16 s]

  const int tid = threadIdx.x;
  const int w = tid >> 6, lane = tid & 63;
  const int l5 = lane >> 5, l31 = lane & 31;
  const int t0 = (blockIdx.x >> 3) * 64;
  const int pair = blockIdx.x & 7;
  const int kvh = pair >> 1, b = pair & 1;
  const int n = 2 * kvh + (w >> 1);
  const int tminw = t0 + 32 * (w & 1), tmaxw = tminw + 31;

  // Q fragments in registers (A-operand: m=l31 row, k-octet=l5)
  bf16x8 aq[16];
  {
    const unsigned short* qrow =
        qb + (((size_t)b * 2048 + tminw + l31) * 8 + n) * 256 + l5 * 8;
#pragma unroll
    for (int kc = 0; kc < 16; ++kc) aq[kc] = *(const bf16x8*)(qrow + kc * 16);
  }

  f32x16 O[8], lsum;
#pragma unroll
  for (int i = 0; i < 8; ++i)
#pragma unroll
    for (int r = 0; r < 16; ++r) O[i][r] = 0.f;
#pragma unroll
  for (int r = 0; r < 16; ++r) lsum[r] = 0.f;

  bf16x8 ones;
#pragma unroll
  for (int i = 0; i < 8; ++i) ones[i] = (short)0x3F80;  // bf16 1.0

  const unsigned short* kbase = kb + ((size_t)b * 8192 + kvh) * 256;
  const unsigned short* vbase = vt + (size_t)(b * 4 + kvh) * 256 * 2048;

  int s_lo = t0 - 1024; if (s_lo < 0) s_lo = 0;
  const int s_end = t0 + 64;

  for (int s0 = s_lo; s0 < s_end; s0 += 32) {
    __syncthreads();  // all waves done reading Kl/Vl from previous step
    // stage K tile (32 s x 256 h) and V tile (256 h x 32 s); 8 GLD16/thread
#pragma unroll
    for (int j = 0; j < 4; ++j) {
      int g = j * 256 + tid;
      int kc = g >> 6, s = (g >> 1) & 31, hi = g & 1;
      GLD16(kbase + (size_t)(s0 + s) * 1024 + kc * 16 + hi * 8,
            Kl + (j * 256 + w * 64) * 8);
    }
#pragma unroll
    for (int j = 0; j < 4; ++j) {
      int g = j * 256 + tid;
      int kc2 = g >> 9, h = (g >> 1) & 255, hi = g & 1;
      GLD16(vbase + (size_t)h * 2048 + s0 + kc2 * 16 + hi * 8,
            Vl + (j * 256 + w * 64) * 8);
    }
    __syncthreads();  // staging complete

    bool skip = (s0 > tmaxw) || (s0 + 31 < tminw - 1023);
    if (!skip) {
      // S = Q K^T (two parallel accumulation chains)
      f32x16 pa, pb;
#pragma unroll
      for (int r = 0; r < 16; ++r) { pa[r] = 0.f; pb[r] = 0.f; }
#pragma unroll
      for (int kc = 0; kc < 16; kc += 2) {
        bf16x8 b0 = *(const bf16x8*)&Kl[kc * 512 + l31 * 16 + l5 * 8];
        bf16x8 b1 = *(const bf16x8*)&Kl[(kc + 1) * 512 + l31 * 16 + l5 * 8];
        pa = __builtin_amdgcn_mfma_f32_32x32x16_bf16(aq[kc], b0, pa, 0, 0, 0);
        pb = __builtin_amdgcn_mfma_f32_32x32x16_bf16(aq[kc + 1], b1, pb, 0, 0, 0);
      }

      bool allvalid = (s0 + 31 <= tminw) && (s0 >= tmaxw - 1023);
      int scol = s0 + l31;
      // P = exp(S), mask -> 0; write to Ps as bf16 (A-layout, wave-private)
#pragma unroll
      for (int r = 0; r < 16; ++r) {
        float sv = pa[r] + pb[r];
        float p = exp2f(sv * 1.442695040888963f);
        int m = (r & 3) + 8 * (r >> 2) + 4 * l5;
        if (!allvalid) {
          int dt = (tminw + m) - scol;
          p = (dt >= 0 && dt < 1024) ? p : 0.f;
        }
        Ps[w * 1024 + (l31 >> 4) * 512 + m * 16 + (l31 & 15)] = f2bf(p);
      }

      // PV + row-sum (wave-private Ps: no barrier needed)
      bf16x8 pf0 = *(const bf16x8*)&Ps[w * 1024 + l31 * 16 + l5 * 8];
      bf16x8 pf1 = *(const bf16x8*)&Ps[w * 1024 + 512 + l31 * 16 + l5 * 8];
      lsum = __builtin_amdgcn_mfma_f32_32x32x16_bf16(pf0, ones, lsum, 0, 0, 0);
      lsum = __builtin_amdgcn_mfma_f32_32x32x16_bf16(pf1, ones, lsum, 0, 0, 0);
#pragma unroll
      for (int hb = 0; hb < 8; ++hb) {
        bf16x8 v0 = *(const bf16x8*)&Vl[(hb * 32 + l31) * 16 + l5 * 8];
        bf16x8 v1 = *(const bf16x8*)&Vl[4096 + (hb * 32 + l31) * 16 + l5 * 8];
        O[hb] = __builtin_amdgcn_mfma_f32_32x32x16_bf16(pf0, v0, O[hb], 0, 0, 0);
        O[hb] = __builtin_amdgcn_mfma_f32_32x32x16_bf16(pf1, v1, O[hb], 0, 0, 0);
      }
    }
  }

  // epilogue: normalize and store bf16
  unsigned short* obase = ob + (((size_t)b * 2048 + tminw) * 8 + n) * 256;
#pragma unroll
  for (int r = 0; r < 16; ++r) {
    int m = (r & 3) + 8 * (r >> 2) + 4 * l5;
    float rinv = 1.0f / lsum[r];
    size_t rowoff = (size_t)m * 2048;
#pragma unroll
    for (int hb = 0; hb < 8; ++hb)
      obase[rowoff + hb * 32 + l31] = f2bf(O[hb][r] * rinv);
  }
}

extern "C" void kernel_launch(void* const* d_in, const int* in_sizes, int n_in,
                              void* d_out, int out_size, void* d_ws, size_t ws_size,
                              hipStream_t stream) {
  const float* x   = (const float*)d_in[0];
  const int* pos   = (const int*)d_in[1];
  const float* q_w = (const float*)d_in[2];
  const float* k_w = (const float*)d_in[3];
  const float* v_w = (const float*)d_in[4];
  const float* o_w = (const float*)d_in[5];
  const float* qns = (const float*)d_in[6];
  const float* kns = (const float*)d_in[7];
  float* out = (float*)d_out;

  unsigned short* W = (unsigned short*)d_ws;
  unsigned short* qb0   = W;               //  8,388,608 us  q bf16
  unsigned short* kb0   = W + 8388608;     //  4,194,304 us  k bf16
  unsigned short* vbf   = W + 12582912;    //  4,194,304 us  v bf16 (row-major)
  unsigned short* vtb   = W + 16777216;    //  4,194,304 us  v^T bf16
  unsigned short* xb    = W + 20971520;    //  8,388,608 us  x bf16
  unsigned short* wqkvt = W + 29360128;    //  8,388,608 us  qkv weights^T
  unsigned short* abuf  = wqkvt;           //  reuse after gemm_qkv
  unsigned short* wot   = W + 37748736;    //  4,194,304 us  o weights^T
  // total 41,943,040 us = 83.9 MB

  cast_bf16<<<dim3(8192), 256, 0, stream>>>(x, xb);
  transpose_wqkv<<<dim3(64, 32), 256, 0, stream>>>(q_w, k_w, v_w, wqkvt);
  gemm_qkv_bf16<<<dim3(32, 32), 256, 0, stream>>>(xb, wqkvt, qb0, kb0, vbf);
  transpose_wo<<<dim3(32, 32), 256, 0, stream>>>(o_w, wot);
  rope_norm_bf16<<<dim3(49152), 64, 0, stream>>>(qb0, kb0, pos, qns, kns);
  transpose_v<<<dim3(4, 32, 8), 256, 0, stream>>>(vbf, vtb);
  attn_mfma<<<dim3(256), 256, 0, stream>>>(qb0, kb0, vtb, abuf);
  gemm_out_bf16<<<dim3(16, 32), 256, 0, stream>>>(abuf, wot, out);
}

// Round 6
// 370.948 us; speedup vs baseline: 7.5221x; 1.0442x over previous
//
#include <hip/hip_runtime.h>
#include <cmath>

#define T_SEQ 2048
#define WINDOW 1024

typedef __attribute__((ext_vector_type(8))) short bf16x8;
typedef __attribute__((ext_vector_type(4))) float f32x4;
typedef __attribute__((ext_vector_type(16))) float f32x16;

__device__ __forceinline__ unsigned short f2bf(float f) {
  union { float f; unsigned int u; } v; v.f = f;
  unsigned int r = v.u + 0x7FFFu + ((v.u >> 16) & 1u);  // RNE
  return (unsigned short)(r >> 16);
}
__device__ __forceinline__ float bf2f(unsigned short u) {
  union { unsigned int i; float f; } v; v.i = ((unsigned int)u) << 16;
  return v.f;
}

#define GLD16(gp, lp)                                                  \
  __builtin_amdgcn_global_load_lds(                                    \
      (__attribute__((address_space(1))) unsigned int*)(gp),           \
      (__attribute__((address_space(3))) unsigned int*)(lp), 16, 0, 0)

// ---------------------------------------------------------------------------
// cast x (fp32) -> bf16
// ---------------------------------------------------------------------------
__global__ __launch_bounds__(256) void cast_bf16(const float* __restrict__ in,
                                                 unsigned short* __restrict__ out) {
  size_t i = (size_t)blockIdx.x * 256 + threadIdx.x;
  float4 v = *(const float4*)&in[i * 4];
  ushort4 o;
  o.x = f2bf(v.x); o.y = f2bf(v.y); o.z = f2bf(v.z); o.w = f2bf(v.w);
  *(ushort4*)&out[i * 4] = o;
}

// ---------------------------------------------------------------------------
// Bt (4096 x 2048) bf16: Bt[c][d] = w[head(c)][d][h(c)] for q|k|v cols.
// ---------------------------------------------------------------------------
__global__ __launch_bounds__(256) void transpose_wqkv(
    const float* __restrict__ qw, const float* __restrict__ kw,
    const float* __restrict__ vw, unsigned short* __restrict__ bt) {
  __shared__ float tile[64][65];
  int c0 = blockIdx.x * 64;
  int d0 = blockIdx.y * 64;
  const float* src; int hbase;
  if (c0 < 2048) { src = qw + (size_t)(c0 >> 8) * 524288; hbase = c0 & 255; }
  else if (c0 < 3072) { int cc = c0 - 2048; src = kw + (size_t)(cc >> 8) * 524288; hbase = cc & 255; }
  else { int cc = c0 - 3072; src = vw + (size_t)(cc >> 8) * 524288; hbase = cc & 255; }
  int tx = threadIdx.x & 15, ty = threadIdx.x >> 4;
#pragma unroll
  for (int p = 0; p < 4; ++p) {
    float4 v = *(const float4*)&src[(size_t)(d0 + ty + 16 * p) * 256 + hbase + tx * 4];
    tile[ty + 16 * p][tx * 4 + 0] = v.x; tile[ty + 16 * p][tx * 4 + 1] = v.y;
    tile[ty + 16 * p][tx * 4 + 2] = v.z; tile[ty + 16 * p][tx * 4 + 3] = v.w;
  }
  __syncthreads();
#pragma unroll
  for (int p = 0; p < 4; ++p) {
    int hh = ty + 16 * p;
    ushort4 o;
    o.x = f2bf(tile[tx * 4 + 0][hh]); o.y = f2bf(tile[tx * 4 + 1][hh]);
    o.z = f2bf(tile[tx * 4 + 2][hh]); o.w = f2bf(tile[tx * 4 + 3][hh]);
    *(ushort4*)&bt[(size_t)(c0 + hh) * 2048 + d0 + tx * 4] = o;
  }
}

// ---------------------------------------------------------------------------
// wot (2048 x 2048) bf16: wot[d][j] = o_w[j][d]  (j = n*256+h)
// ---------------------------------------------------------------------------
__global__ __launch_bounds__(256) void transpose_wo(
    const float* __restrict__ ow, unsigned short* __restrict__ wot) {
  __shared__ float tile[64][65];
  int j0 = blockIdx.x * 64;
  int d0 = blockIdx.y * 64;
  int tx = threadIdx.x & 15, ty = threadIdx.x >> 4;
#pragma unroll
  for (int p = 0; p < 4; ++p) {
    float4 v = *(const float4*)&ow[(size_t)(j0 + ty + 16 * p) * 2048 + d0 + tx * 4];
    tile[ty + 16 * p][tx * 4 + 0] = v.x; tile[ty + 16 * p][tx * 4 + 1] = v.y;
    tile[ty + 16 * p][tx * 4 + 2] = v.z; tile[ty + 16 * p][tx * 4 + 3] = v.w;
  }
  __syncthreads();
#pragma unroll
  for (int p = 0; p < 4; ++p) {
    int hh = ty + 16 * p;
    ushort4 o;
    o.x = f2bf(tile[tx * 4 + 0][hh]); o.y = f2bf(tile[tx * 4 + 1][hh]);
    o.z = f2bf(tile[tx * 4 + 2][hh]); o.w = f2bf(tile[tx * 4 + 3][hh]);
    *(ushort4*)&wot[(size_t)(d0 + hh) * 2048 + j0 + tx * 4] = o;
  }
}

// ---------------------------------------------------------------------------
// m97-style bf16 MFMA GEMM core (16x16x32), 128x128 tile.
// ---------------------------------------------------------------------------
__device__ __forceinline__ void gemm128_core(
    const unsigned short* __restrict__ A, const unsigned short* __restrict__ Bt,
    unsigned short* As, unsigned short* Bs, int m0, int n0, int K,
    f32x4 acc[4][4]) {
  const int tid = threadIdx.x;
  const int wave = tid >> 6, lane = tid & 63;
  const int wm = (wave & 1) << 6, wn = (wave >> 1) << 6;
  const int i0 = wave * 2, i1 = wave * 2 + 1;
  const int sr = lane >> 2;
  const int sc = (lane & 3) * 8;
  const size_t ar0 = (size_t)(m0 + i0 * 16 + sr) * K + sc;
  const size_t ar1 = (size_t)(m0 + i1 * 16 + sr) * K + sc;
  const size_t br0 = (size_t)(n0 + i0 * 16 + sr) * K + sc;
  const size_t br1 = (size_t)(n0 + i1 * 16 + sr) * K + sc;
  const int fm = lane & 15, fk = (lane >> 4) * 8;

  for (int kt = 0; kt < K; kt += 32) {
    GLD16(A + ar0 + kt, As + i0 * 512);
    GLD16(A + ar1 + kt, As + i1 * 512);
    GLD16(Bt + br0 + kt, Bs + i0 * 512);
    GLD16(Bt + br1 + kt, Bs + i1 * 512);
    __syncthreads();
    bf16x8 af[4], bv[4];
#pragma unroll
    for (int i = 0; i < 4; ++i)
      af[i] = *(const bf16x8*)&As[(wm + i * 16 + fm) * 32 + fk];
#pragma unroll
    for (int j = 0; j < 4; ++j)
      bv[j] = *(const bf16x8*)&Bs[(wn + j * 16 + fm) * 32 + fk];
#pragma unroll
    for (int i = 0; i < 4; ++i)
#pragma unroll
      for (int j = 0; j < 4; ++j)
        acc[i][j] = __builtin_amdgcn_mfma_f32_16x16x32_bf16(af[i], bv[j], acc[i][j], 0, 0, 0);
    __syncthreads();
  }
}

// QKV projection -> bf16 outputs qb0[b][t][8][256], kb0[b][t][4][256], vbf[b][t][4][256]
__global__ __launch_bounds__(256) void gemm_qkv_bf16(
    const unsigned short* __restrict__ xb, const unsigned short* __restrict__ wt,
    unsigned short* __restrict__ qo, unsigned short* __restrict__ ko,
    unsigned short* __restrict__ vo) {
  __shared__ unsigned short As[128 * 32];
  __shared__ unsigned short Bs[128 * 32];
  const int n0 = blockIdx.x * 128, m0 = blockIdx.y * 128;
  f32x4 acc[4][4];
#pragma unroll
  for (int i = 0; i < 4; ++i)
#pragma unroll
    for (int j = 0; j < 4; ++j) acc[i][j] = {0.f, 0.f, 0.f, 0.f};
  gemm128_core(xb, wt, As, Bs, m0, n0, 2048, acc);

  unsigned short* obase; int ldo, cb;
  if (n0 < 2048) { obase = qo; ldo = 2048; cb = n0; }
  else if (n0 < 3072) { obase = ko; ldo = 1024; cb = n0 - 2048; }
  else { obase = vo; ldo = 1024; cb = n0 - 3072; }
  const int lane = threadIdx.x & 63, wave = threadIdx.x >> 6;
  const int wm = (wave & 1) << 6, wn = (wave >> 1) << 6;
  const int rbase = m0 + wm + (lane >> 4) * 4;
  const int cbase = cb + wn + (lane & 15);
#pragma unroll
  for (int i = 0; i < 4; ++i)
#pragma unroll
    for (int j = 0; j < 4; ++j)
#pragma unroll
      for (int r = 0; r < 4; ++r)
        obase[(size_t)(rbase + i * 16 + r) * ldo + cbase + j * 16] = f2bf(acc[i][j][r]);
}

// Output projection: abuf(4096x2048 bf16) @ wot^T -> out fp32
__global__ __launch_bounds__(256) void gemm_out_bf16(
    const unsigned short* __restrict__ ab, const unsigned short* __restrict__ wot,
    float* __restrict__ out) {
  __shared__ unsigned short As[128 * 32];
  __shared__ unsigned short Bs[128 * 32];
  const int n0 = blockIdx.x * 128, m0 = blockIdx.y * 128;
  f32x4 acc[4][4];
#pragma unroll
  for (int i = 0; i < 4; ++i)
#pragma unroll
    for (int j = 0; j < 4; ++j) acc[i][j] = {0.f, 0.f, 0.f, 0.f};
  gemm128_core(ab, wot, As, Bs, m0, n0, 2048, acc);

  const int lane = threadIdx.x & 63, wave = threadIdx.x >> 6;
  const int wm = (wave & 1) << 6, wn = (wave >> 1) << 6;
  const int rbase = m0 + wm + (lane >> 4) * 4;
  const int cbase = n0 + wn + (lane & 15);
#pragma unroll
  for (int i = 0; i < 4; ++i)
#pragma unroll
    for (int j = 0; j < 4; ++j)
#pragma unroll
      for (int r = 0; r < 4; ++r)
        out[(size_t)(rbase + i * 16 + r) * 2048 + cbase + j * 16] = acc[i][j][r];
}

// ---------------------------------------------------------------------------
// RMSNorm + RoPE, in-place on bf16 rows (q: scale 1/16 folded in; k: 1.0).
// ---------------------------------------------------------------------------
__global__ __launch_bounds__(64) void rope_norm_bf16(
    unsigned short* __restrict__ qb, unsigned short* __restrict__ kb,
    const int* __restrict__ positions,
    const float* __restrict__ qns, const float* __restrict__ kns) {
  int row = blockIdx.x;
  int lane = threadIdx.x;
  unsigned short* ptr; const float* ns; float extra; int bt;
  if (row < 32768) {
    ptr = qb + (size_t)row * 256; ns = qns; extra = 0.0625f; bt = row >> 3;
  } else {
    int r = row - 32768;
    ptr = kb + (size_t)r * 256; ns = kns; extra = 1.0f; bt = r >> 2;
  }
  int pos = positions[bt];

  ushort4 u = *(const ushort4*)&ptr[lane << 2];
  float xv[4] = {bf2f(u.x), bf2f(u.y), bf2f(u.z), bf2f(u.w)};
  float ss = xv[0]*xv[0] + xv[1]*xv[1] + xv[2]*xv[2] + xv[3]*xv[3];
#pragma unroll
  for (int off = 1; off < 64; off <<= 1) ss += __shfl_xor(ss, off, 64);
  float rinv = rsqrtf(ss * (1.0f / 256.0f) + 1e-6f);

  float4 sc4 = *(const float4*)&ns[lane << 2];
  xv[0] *= rinv * (1.0f + sc4.x);
  xv[1] *= rinv * (1.0f + sc4.y);
  xv[2] *= rinv * (1.0f + sc4.z);
  xv[3] *= rinv * (1.0f + sc4.w);

  float ov[4];
#pragma unroll
  for (int c = 0; c < 4; ++c) ov[c] = __shfl_xor(xv[c], 32, 64);

  int hr = (lane & 31) << 2;
  float sgn = (lane < 32) ? -1.0f : 1.0f;
  ushort4 w;
  unsigned short res[4];
#pragma unroll
  for (int c = 0; c < 4; ++c) {
    float invts = exp2f(-(float)(hr + c) * 0.10381025296523007f);
    float angle = (float)pos * invts;
    float sn, cs;
    __sincosf(angle, &sn, &cs);
    res[c] = f2bf((xv[c] * cs + sgn * ov[c] * sn) * extra);
  }
  w.x = res[0]; w.y = res[1]; w.z = res[2]; w.w = res[3];
  *(ushort4*)&ptr[lane << 2] = w;
}

// ---------------------------------------------------------------------------
// V transpose: vbf[b][t][kvh][256] -> vt[b][kvh][256][2048] (bf16)
// ---------------------------------------------------------------------------
__global__ __launch_bounds__(256) void transpose_v(
    const unsigned short* __restrict__ vbf, unsigned short* __restrict__ vt) {
  __shared__ unsigned short tile[64][68];
  int h0 = blockIdx.x * 64;
  int t0 = blockIdx.y * 64;
  int z = blockIdx.z;  // b*4 + kvh
  int tx = threadIdx.x & 15, ty = threadIdx.x >> 4;
  const unsigned short* src = vbf + ((size_t)(z >> 2) * 8192 + (z & 3)) * 256;
#pragma unroll
  for (int p = 0; p < 4; ++p) {
    ushort4 v = *(const ushort4*)&src[(size_t)(t0 + ty + 16 * p) * 1024 + h0 + tx * 4];
    tile[ty + 16 * p][tx * 4 + 0] = v.x; tile[ty + 16 * p][tx * 4 + 1] = v.y;
    tile[ty + 16 * p][tx * 4 + 2] = v.z; tile[ty + 16 * p][tx * 4 + 3] = v.w;
  }
  __syncthreads();
  unsigned short* dst = vt + (size_t)z * 256 * 2048;
#pragma unroll
  for (int p = 0; p < 4; ++p) {
    int hh = ty + 16 * p;
    ushort4 o;
    o.x = tile[tx * 4 + 0][hh]; o.y = tile[tx * 4 + 1][hh];
    o.z = tile[tx * 4 + 2][hh]; o.w = tile[tx * 4 + 3][hh];
    *(ushort4*)&dst[(size_t)(h0 + hh) * 2048 + t0 + tx * 4] = o;
  }
}

// ---------------------------------------------------------------------------
// MFMA sliding-window attention, 32x32x16 bf16, static-max softmax.
// Block = 128 thr = 2 waves: wave w -> head 2*kvh + w, q-rows [t0, t0+32).
// K/V staged once per block, shared by both waves (GQA sharing).
// Grid 512 = 2 blocks/CU: independent blocks overlap staging latency with
// compute (the R5 1-block/CU layout serialized drain+compute every step).
// XCD swizzle: blockIdx.x & 7 = (kvh,b) pair keeps K/V in one XCD's L2.
// ---------------------------------------------------------------------------
__global__ __launch_bounds__(128) void attn_mfma(
    const unsigned short* __restrict__ qb,  // [b][t][8][256]
    const unsigned short* __restrict__ kb,  // [b][t][4][256]
    const unsigned short* __restrict__ vt,  // [b][4][256][2048]
    unsigned short* __restrict__ ob) {      // [b][t][8][256]
  __shared__ __align__(16) unsigned short Kl[8192];   // [kc16][32 s][16 h]
  __shared__ __align__(16) unsigned short Vl[8192];   // [kc2][256 h][16 s]
  __shared__ __align__(16) unsigned short Ps[2048];   // [w][kc2][32 m][16 s]

  const int tid = threadIdx.x;
  const int w = tid >> 6, lane = tid & 63;
  const int l5 = lane >> 5, l31 = lane & 31;
  const int pair = blockIdx.x & 7;
  const int t0 = (blockIdx.x >> 3) * 32;
  const int kvh = pair >> 1, b = pair & 1;
  const int n = 2 * kvh + w;
  const int tmin = t0, tmax = t0 + 31;

  // Q fragments in registers (A-operand: m=l31 row, k-octet=l5)
  bf16x8 aq[16];
  {
    const unsigned short* qrow =
        qb + (((size_t)b * 2048 + tmin + l31) * 8 + n) * 256 + l5 * 8;
#pragma unroll
    for (int kc = 0; kc < 16; ++kc) aq[kc] = *(const bf16x8*)(qrow + kc * 16);
  }

  f32x16 O[8], lsum;
#pragma unroll
  for (int i = 0; i < 8; ++i)
#pragma unroll
    for (int r = 0; r < 16; ++r) O[i][r] = 0.f;
#pragma unroll
  for (int r = 0; r < 16; ++r) lsum[r] = 0.f;

  bf16x8 ones;
#pragma unroll
  for (int i = 0; i < 8; ++i) ones[i] = (short)0x3F80;  // bf16 1.0

  const unsigned short* kbase = kb + ((size_t)b * 8192 + kvh) * 256;
  const unsigned short* vbase = vt + (size_t)(b * 4 + kvh) * 256 * 2048;

  int s_lo = t0 - 1024; if (s_lo < 0) s_lo = 0;
  const int s_end = t0 + 32;

  for (int s0 = s_lo; s0 < s_end; s0 += 32) {
    __syncthreads();  // both waves done reading Kl/Vl from previous step
    // stage K tile (32 s x 256 h) and V tile (256 h x 32 s); 16 GLD16/thread
#pragma unroll
    for (int j = 0; j < 8; ++j) {
      int g = j * 128 + tid;
      int kc = g >> 6, s = (g >> 1) & 31, hi = g & 1;
      GLD16(kbase + (size_t)(s0 + s) * 1024 + kc * 16 + hi * 8,
            Kl + (j * 128 + w * 64) * 8);
    }
#pragma unroll
    for (int j = 0; j < 8; ++j) {
      int g = j * 128 + tid;
      int kc2 = g >> 9, h = (g >> 1) & 255, hi = g & 1;
      GLD16(vbase + (size_t)h * 2048 + s0 + kc2 * 16 + hi * 8,
            Vl + (j * 128 + w * 64) * 8);
    }
    __syncthreads();  // staging complete

    // S = Q K^T (two parallel accumulation chains)
    f32x16 pa, pb;
#pragma unroll
    for (int r = 0; r < 16; ++r) { pa[r] = 0.f; pb[r] = 0.f; }
#pragma unroll
    for (int kc = 0; kc < 16; kc += 2) {
      bf16x8 b0 = *(const bf16x8*)&Kl[kc * 512 + l31 * 16 + l5 * 8];
      bf16x8 b1 = *(const bf16x8*)&Kl[(kc + 1) * 512 + l31 * 16 + l5 * 8];
      pa = __builtin_amdgcn_mfma_f32_32x32x16_bf16(aq[kc], b0, pa, 0, 0, 0);
      pb = __builtin_amdgcn_mfma_f32_32x32x16_bf16(aq[kc + 1], b1, pb, 0, 0, 0);
    }

    bool allvalid = (s0 + 31 <= tmin) && (s0 >= tmax - 1023);
    int scol = s0 + l31;
    // P = exp(S), mask -> 0; write to Ps as bf16 (A-layout, wave-private)
#pragma unroll
    for (int r = 0; r < 16; ++r) {
      float sv = pa[r] + pb[r];
      float p = exp2f(sv * 1.442695040888963f);
      int m = (r & 3) + 8 * (r >> 2) + 4 * l5;
      if (!allvalid) {
        int dt = (tmin + m) - scol;
        p = (dt >= 0 && dt < 1024) ? p : 0.f;
      }
      Ps[w * 1024 + (l31 >> 4) * 512 + m * 16 + (l31 & 15)] = f2bf(p);
    }

    // PV + row-sum (wave-private Ps: no barrier needed)
    bf16x8 pf0 = *(const bf16x8*)&Ps[w * 1024 + l31 * 16 + l5 * 8];
    bf16x8 pf1 = *(const bf16x8*)&Ps[w * 1024 + 512 + l31 * 16 + l5 * 8];
    lsum = __builtin_amdgcn_mfma_f32_32x32x16_bf16(pf0, ones, lsum, 0, 0, 0);
    lsum = __builtin_amdgcn_mfma_f32_32x32x16_bf16(pf1, ones, lsum, 0, 0, 0);
#pragma unroll
    for (int hb = 0; hb < 8; ++hb) {
      bf16x8 v0 = *(const bf16x8*)&Vl[(hb * 32 + l31) * 16 + l5 * 8];
      bf16x8 v1 = *(const bf16x8*)&Vl[4096 + (hb * 32 + l31) * 16 + l5 * 8];
      O[hb] = __builtin_amdgcn_mfma_f32_32x32x16_bf16(pf0, v0, O[hb], 0, 0, 0);
      O[hb] = __builtin_amdgcn_mfma_f32_32x32x16_bf16(pf1, v1, O[hb], 0, 0, 0);
    }
  }

  // epilogue: normalize and store bf16
  unsigned short* obase = ob + (((size_t)b * 2048 + tmin) * 8 + n) * 256;
#pragma unroll
  for (int r = 0; r < 16; ++r) {
    int m = (r & 3) + 8 * (r >> 2) + 4 * l5;
    float rinv = 1.0f / lsum[r];
    size_t rowoff = (size_t)m * 2048;
#pragma unroll
    for (int hb = 0; hb < 8; ++hb)
      obase[rowoff + hb * 32 + l31] = f2bf(O[hb][r] * rinv);
  }
}

extern "C" void kernel_launch(void* const* d_in, const int* in_sizes, int n_in,
                              void* d_out, int out_size, void* d_ws, size_t ws_size,
                              hipStream_t stream) {
  const float* x   = (const float*)d_in[0];
  const int* pos   = (const int*)d_in[1];
  const float* q_w = (const float*)d_in[2];
  const float* k_w = (const float*)d_in[3];
  const float* v_w = (const float*)d_in[4];
  const float* o_w = (const float*)d_in[5];
  const float* qns = (const float*)d_in[6];
  const float* kns = (const float*)d_in[7];
  float* out = (float*)d_out;

  unsigned short* W = (unsigned short*)d_ws;
  unsigned short* qb0   = W;               //  8,388,608 us  q bf16
  unsigned short* kb0   = W + 8388608;     //  4,194,304 us  k bf16
  unsigned short* vbf   = W + 12582912;    //  4,194,304 us  v bf16 (row-major)
  unsigned short* vtb   = W + 16777216;    //  4,194,304 us  v^T bf16
  unsigned short* xb    = W + 20971520;    //  8,388,608 us  x bf16
  unsigned short* wqkvt = W + 29360128;    //  8,388,608 us  qkv weights^T
  unsigned short* abuf  = wqkvt;           //  reuse after gemm_qkv
  unsigned short* wot   = W + 37748736;    //  4,194,304 us  o weights^T
  // total 41,943,040 us = 83.9 MB

  cast_bf16<<<dim3(8192), 256, 0, stream>>>(x, xb);
  transpose_wqkv<<<dim3(64, 32), 256, 0, stream>>>(q_w, k_w, v_w, wqkvt);
  gemm_qkv_bf16<<<dim3(32, 32), 256, 0, stream>>>(xb, wqkvt, qb0, kb0, vbf);
  transpose_wo<<<dim3(32, 32), 256, 0, stream>>>(o_w, wot);
  rope_norm_bf16<<<dim3(49152), 64, 0, stream>>>(qb0, kb0, pos, qns, kns);
  transpose_v<<<dim3(4, 32, 8), 256, 0, stream>>>(vbf, vtb);
  attn_mfma<<<dim3(512), 128, 0, stream>>>(qb0, kb0, vtb, abuf);
  gemm_out_bf16<<<dim3(16, 32), 256, 0, stream>>>(abuf, wot, out);
}

// Round 7
// 360.517 us; speedup vs baseline: 7.7398x; 1.0289x over previous
//
#include <hip/hip_runtime.h>
#include <cmath>

#define T_SEQ 2048
#define WINDOW 1024

typedef __attribute__((ext_vector_type(8))) short bf16x8;
typedef __attribute__((ext_vector_type(4))) float f32x4;
typedef __attribute__((ext_vector_type(16))) float f32x16;

__device__ __forceinline__ unsigned short f2bf(float f) {
  union { float f; unsigned int u; } v; v.f = f;
  unsigned int r = v.u + 0x7FFFu + ((v.u >> 16) & 1u);  // RNE
  return (unsigned short)(r >> 16);
}
__device__ __forceinline__ float bf2f(unsigned short u) {
  union { unsigned int i; float f; } v; v.i = ((unsigned int)u) << 16;
  return v.f;
}

#define GLD16(gp, lp)                                                  \
  __builtin_amdgcn_global_load_lds(                                    \
      (__attribute__((address_space(1))) unsigned int*)(gp),           \
      (__attribute__((address_space(3))) unsigned int*)(lp), 16, 0, 0)

// ---------------------------------------------------------------------------
// prep: fused cast_bf16(x) + transpose_wqkv + transpose_wo.
//   blocks [0,8192):      cast x -> xb (1024 elems/block)
//   blocks [8192,10240):  wqkvt[c][d] = w[head(c)][d][h(c)]   (64x64 tiles)
//   blocks [10240,11264): wot[d][j]   = o_w[j][d]             (64x64 tiles)
// ---------------------------------------------------------------------------
__global__ __launch_bounds__(256) void prep(
    const float* __restrict__ x,
    const float* __restrict__ qw, const float* __restrict__ kw,
    const float* __restrict__ vw, const float* __restrict__ ow,
    unsigned short* __restrict__ xb, unsigned short* __restrict__ wqkvt,
    unsigned short* __restrict__ wot) {
  __shared__ float tile[64][65];
  const int blk = blockIdx.x;
  const int tid = threadIdx.x;
  if (blk < 8192) {
    size_t i = (size_t)blk * 256 + tid;
    float4 v = *(const float4*)&x[i * 4];
    ushort4 o;
    o.x = f2bf(v.x); o.y = f2bf(v.y); o.z = f2bf(v.z); o.w = f2bf(v.w);
    *(ushort4*)&xb[i * 4] = o;
    return;
  }
  int tx = tid & 15, ty = tid >> 4;
  if (blk < 10240) {
    int idx = blk - 8192;
    int c0 = (idx & 63) * 64, d0 = (idx >> 6) * 64;
    const float* src; int hbase;
    if (c0 < 2048) { src = qw + (size_t)(c0 >> 8) * 524288; hbase = c0 & 255; }
    else if (c0 < 3072) { int cc = c0 - 2048; src = kw + (size_t)(cc >> 8) * 524288; hbase = cc & 255; }
    else { int cc = c0 - 3072; src = vw + (size_t)(cc >> 8) * 524288; hbase = cc & 255; }
#pragma unroll
    for (int p = 0; p < 4; ++p) {
      float4 v = *(const float4*)&src[(size_t)(d0 + ty + 16 * p) * 256 + hbase + tx * 4];
      tile[ty + 16 * p][tx * 4 + 0] = v.x; tile[ty + 16 * p][tx * 4 + 1] = v.y;
      tile[ty + 16 * p][tx * 4 + 2] = v.z; tile[ty + 16 * p][tx * 4 + 3] = v.w;
    }
    __syncthreads();
#pragma unroll
    for (int p = 0; p < 4; ++p) {
      int hh = ty + 16 * p;
      ushort4 o;
      o.x = f2bf(tile[tx * 4 + 0][hh]); o.y = f2bf(tile[tx * 4 + 1][hh]);
      o.z = f2bf(tile[tx * 4 + 2][hh]); o.w = f2bf(tile[tx * 4 + 3][hh]);
      *(ushort4*)&wqkvt[(size_t)(c0 + hh) * 2048 + d0 + tx * 4] = o;
    }
  } else {
    int idx = blk - 10240;
    int j0 = (idx & 31) * 64, d0 = (idx >> 5) * 64;
#pragma unroll
    for (int p = 0; p < 4; ++p) {
      float4 v = *(const float4*)&ow[(size_t)(j0 + ty + 16 * p) * 2048 + d0 + tx * 4];
      tile[ty + 16 * p][tx * 4 + 0] = v.x; tile[ty + 16 * p][tx * 4 + 1] = v.y;
      tile[ty + 16 * p][tx * 4 + 2] = v.z; tile[ty + 16 * p][tx * 4 + 3] = v.w;
    }
    __syncthreads();
#pragma unroll
    for (int p = 0; p < 4; ++p) {
      int hh = ty + 16 * p;
      ushort4 o;
      o.x = f2bf(tile[tx * 4 + 0][hh]); o.y = f2bf(tile[tx * 4 + 1][hh]);
      o.z = f2bf(tile[tx * 4 + 2][hh]); o.w = f2bf(tile[tx * 4 + 3][hh]);
      *(ushort4*)&wot[(size_t)(d0 + hh) * 2048 + j0 + tx * 4] = o;
    }
  }
}

// ---------------------------------------------------------------------------
// m97-style bf16 MFMA GEMM core (16x16x32), 128x128 tile.
// ---------------------------------------------------------------------------
__device__ __forceinline__ void gemm128_core(
    const unsigned short* __restrict__ A, const unsigned short* __restrict__ Bt,
    unsigned short* As, unsigned short* Bs, int m0, int n0, int K,
    f32x4 acc[4][4]) {
  const int tid = threadIdx.x;
  const int wave = tid >> 6, lane = tid & 63;
  const int wm = (wave & 1) << 6, wn = (wave >> 1) << 6;
  const int i0 = wave * 2, i1 = wave * 2 + 1;
  const int sr = lane >> 2;
  const int sc = (lane & 3) * 8;
  const size_t ar0 = (size_t)(m0 + i0 * 16 + sr) * K + sc;
  const size_t ar1 = (size_t)(m0 + i1 * 16 + sr) * K + sc;
  const size_t br0 = (size_t)(n0 + i0 * 16 + sr) * K + sc;
  const size_t br1 = (size_t)(n0 + i1 * 16 + sr) * K + sc;
  const int fm = lane & 15, fk = (lane >> 4) * 8;

  for (int kt = 0; kt < K; kt += 32) {
    GLD16(A + ar0 + kt, As + i0 * 512);
    GLD16(A + ar1 + kt, As + i1 * 512);
    GLD16(Bt + br0 + kt, Bs + i0 * 512);
    GLD16(Bt + br1 + kt, Bs + i1 * 512);
    __syncthreads();
    bf16x8 af[4], bv[4];
#pragma unroll
    for (int i = 0; i < 4; ++i)
      af[i] = *(const bf16x8*)&As[(wm + i * 16 + fm) * 32 + fk];
#pragma unroll
    for (int j = 0; j < 4; ++j)
      bv[j] = *(const bf16x8*)&Bs[(wn + j * 16 + fm) * 32 + fk];
#pragma unroll
    for (int i = 0; i < 4; ++i)
#pragma unroll
      for (int j = 0; j < 4; ++j)
        acc[i][j] = __builtin_amdgcn_mfma_f32_16x16x32_bf16(af[i], bv[j], acc[i][j], 0, 0, 0);
    __syncthreads();
  }
}

// QKV projection -> bf16 qb0[b][t][8][256], kb0[b][t][4][256], vbf[b][t][4][256]
__global__ __launch_bounds__(256) void gemm_qkv_bf16(
    const unsigned short* __restrict__ xb, const unsigned short* __restrict__ wt,
    unsigned short* __restrict__ qo, unsigned short* __restrict__ ko,
    unsigned short* __restrict__ vo) {
  __shared__ unsigned short As[128 * 32];
  __shared__ unsigned short Bs[128 * 32];
  const int n0 = blockIdx.x * 128, m0 = blockIdx.y * 128;
  f32x4 acc[4][4];
#pragma unroll
  for (int i = 0; i < 4; ++i)
#pragma unroll
    for (int j = 0; j < 4; ++j) acc[i][j] = {0.f, 0.f, 0.f, 0.f};
  gemm128_core(xb, wt, As, Bs, m0, n0, 2048, acc);

  unsigned short* obase; int ldo, cb;
  if (n0 < 2048) { obase = qo; ldo = 2048; cb = n0; }
  else if (n0 < 3072) { obase = ko; ldo = 1024; cb = n0 - 2048; }
  else { obase = vo; ldo = 1024; cb = n0 - 3072; }
  const int lane = threadIdx.x & 63, wave = threadIdx.x >> 6;
  const int wm = (wave & 1) << 6, wn = (wave >> 1) << 6;
  const int rbase = m0 + wm + (lane >> 4) * 4;
  const int cbase = cb + wn + (lane & 15);
#pragma unroll
  for (int i = 0; i < 4; ++i)
#pragma unroll
    for (int j = 0; j < 4; ++j)
#pragma unroll
      for (int r = 0; r < 4; ++r)
        obase[(size_t)(rbase + i * 16 + r) * ldo + cbase + j * 16] = f2bf(acc[i][j][r]);
}

// Output projection: abuf(4096x2048 bf16) @ wot^T -> out fp32
__global__ __launch_bounds__(256) void gemm_out_bf16(
    const unsigned short* __restrict__ ab, const unsigned short* __restrict__ wot,
    float* __restrict__ out) {
  __shared__ unsigned short As[128 * 32];
  __shared__ unsigned short Bs[128 * 32];
  const int n0 = blockIdx.x * 128, m0 = blockIdx.y * 128;
  f32x4 acc[4][4];
#pragma unroll
  for (int i = 0; i < 4; ++i)
#pragma unroll
    for (int j = 0; j < 4; ++j) acc[i][j] = {0.f, 0.f, 0.f, 0.f};
  gemm128_core(ab, wot, As, Bs, m0, n0, 2048, acc);

  const int lane = threadIdx.x & 63, wave = threadIdx.x >> 6;
  const int wm = (wave & 1) << 6, wn = (wave >> 1) << 6;
  const int rbase = m0 + wm + (lane >> 4) * 4;
  const int cbase = n0 + wn + (lane & 15);
#pragma unroll
  for (int i = 0; i < 4; ++i)
#pragma unroll
    for (int j = 0; j < 4; ++j)
#pragma unroll
      for (int r = 0; r < 4; ++r)
        out[(size_t)(rbase + i * 16 + r) * 2048 + cbase + j * 16] = acc[i][j][r];
}

// ---------------------------------------------------------------------------
// postproc: fused RMSNorm+RoPE (q in-place, k -> swizzled panels) + V panelize.
//   blocks [0,12288):      rope, 4 waves/block, 1 row/wave (49152 rows)
//   blocks [12288,13312):  V transpose into swizzled panels
// K panel layout (per b,kvh,p=t/32): [s=t%32][chunk c^s][16B] — 16 KB, equals
// the attention LDS image, so attn staging is an identity coalesced copy.
// V panel layout (per b,kvh,p): [h 256][chunk c^(h&3)][16B] — 16 KB.
// ---------------------------------------------------------------------------
__global__ __launch_bounds__(256) void postproc(
    unsigned short* __restrict__ qb, const unsigned short* __restrict__ kb,
    unsigned short* __restrict__ kpan,
    const unsigned short* __restrict__ vbf, unsigned short* __restrict__ vpan,
    const int* __restrict__ positions,
    const float* __restrict__ qns, const float* __restrict__ kns) {
  const int blk = blockIdx.x;
  const int tid = threadIdx.x;
  if (blk < 12288) {
    int row = blk * 4 + (tid >> 6);
    int lane = tid & 63;
    const unsigned short* src; const float* ns; float extra; int bt;
    bool isq = row < 32768;
    if (isq) {
      src = qb + (size_t)row * 256; ns = qns; extra = 0.0625f; bt = row >> 3;
    } else {
      int r = row - 32768;
      src = kb + (size_t)r * 256; ns = kns; extra = 1.0f; bt = r >> 2;
    }
    int pos = positions[bt];

    ushort4 u = *(const ushort4*)&src[lane << 2];
    float xv[4] = {bf2f(u.x), bf2f(u.y), bf2f(u.z), bf2f(u.w)};
    float ss = xv[0]*xv[0] + xv[1]*xv[1] + xv[2]*xv[2] + xv[3]*xv[3];
#pragma unroll
    for (int off = 1; off < 64; off <<= 1) ss += __shfl_xor(ss, off, 64);
    float rinv = rsqrtf(ss * (1.0f / 256.0f) + 1e-6f);

    float4 sc4 = *(const float4*)&ns[lane << 2];
    xv[0] *= rinv * (1.0f + sc4.x);
    xv[1] *= rinv * (1.0f + sc4.y);
    xv[2] *= rinv * (1.0f + sc4.z);
    xv[3] *= rinv * (1.0f + sc4.w);

    float ov[4];
#pragma unroll
    for (int c = 0; c < 4; ++c) ov[c] = __shfl_xor(xv[c], 32, 64);

    int hr = (lane & 31) << 2;
    float sgn = (lane < 32) ? -1.0f : 1.0f;
    ushort4 w4;
    unsigned short res[4];
#pragma unroll
    for (int c = 0; c < 4; ++c) {
      float invts = exp2f(-(float)(hr + c) * 0.10381025296523007f);
      float angle = (float)pos * invts;
      float sn, cs;
      __sincosf(angle, &sn, &cs);
      res[c] = f2bf((xv[c] * cs + sgn * ov[c] * sn) * extra);
    }
    w4.x = res[0]; w4.y = res[1]; w4.z = res[2]; w4.w = res[3];
    if (isq) {
      *(ushort4*)&qb[(size_t)row * 256 + (lane << 2)] = w4;
    } else {
      int r = row - 32768;
      int kvh = r & 3;
      int b_ = bt >> 11, t = bt & 2047;
      unsigned short* pan = kpan + (((size_t)(b_ * 4 + kvh) * 64 + (t >> 5)) * 8192);
      int s = t & 31;
      int c = lane >> 1;
      size_t el = (size_t)s * 256 + (size_t)((c ^ s) & 31) * 8 + (lane & 1) * 4;
      *(ushort4*)&pan[el] = w4;
    }
    return;
  }
  // ---- V panelize ----
  __shared__ unsigned short tile[64][68];
  int idx = blk - 12288;
  int h0 = (idx & 3) * 64;
  int t0 = ((idx >> 2) & 31) * 64;
  int z = idx >> 7;  // b*4 + kvh
  int tx = tid & 15, ty = tid >> 4;
  const unsigned short* src = vbf + ((size_t)(z >> 2) * 8192 + (z & 3)) * 256;
#pragma unroll
  for (int p = 0; p < 4; ++p) {
    ushort4 v = *(const ushort4*)&src[(size_t)(t0 + ty + 16 * p) * 1024 + h0 + tx * 4];
    tile[ty + 16 * p][tx * 4 + 0] = v.x; tile[ty + 16 * p][tx * 4 + 1] = v.y;
    tile[ty + 16 * p][tx * 4 + 2] = v.z; tile[ty + 16 * p][tx * 4 + 3] = v.w;
  }
  __syncthreads();
#pragma unroll
  for (int p = 0; p < 4; ++p) {
    int hh = ty + 16 * p;
    int h = h0 + hh;
    int t = t0 + tx * 4;
    int pp = t >> 5, s = t & 31;
    ushort4 o;
    o.x = tile[tx * 4 + 0][hh]; o.y = tile[tx * 4 + 1][hh];
    o.z = tile[tx * 4 + 2][hh]; o.w = tile[tx * 4 + 3][hh];
    size_t el = ((size_t)z * 64 + pp) * 8192 + (size_t)h * 32 +
                (size_t)(((s >> 3) ^ (h & 3)) & 3) * 8 + (s & 7);
    *(ushort4*)&vpan[el] = o;
  }
}

// ---------------------------------------------------------------------------
// MFMA sliding-window attention, 32x32x16 bf16, static-max softmax.
// Block = 128 thr = 2 waves: wave w -> head 2*kvh + w, q-rows [t0, t0+32).
// K/V staged from pre-swizzled 16 KB panels: identity, fully-coalesced GLD16.
// B-frag ds_read_b128 conflict-free via XOR chunk swizzle; Ps stride 24.
// XCD swizzle: blockIdx.x & 7 = (kvh,b) keeps K/V panels in one XCD's L2.
// ---------------------------------------------------------------------------
__global__ __launch_bounds__(128) void attn_mfma(
    const unsigned short* __restrict__ qb,    // [b][t][8][256]
    const unsigned short* __restrict__ kpan,  // [b*4+kvh][p][32 s][swz 512B]
    const unsigned short* __restrict__ vpan,  // [b*4+kvh][p][256 h][swz 64B]
    unsigned short* __restrict__ ob) {        // [b][t][8][256]
  __shared__ __align__(16) unsigned short Kl[8192];  // [s 32][chunk 32][8]
  __shared__ __align__(16) unsigned short Vl[8192];  // [h 256][chunk 4][8]
  __shared__ __align__(16) unsigned short Ps[3072];  // [w][half 2][m 32][24]

  const int tid = threadIdx.x;
  const int w = tid >> 6, lane = tid & 63;
  const int l5 = lane >> 5, l31 = lane & 31;
  const int pair = blockIdx.x & 7;
  const int t0 = (blockIdx.x >> 3) * 32;
  const int kvh = pair >> 1, b = pair & 1;
  const int n = 2 * kvh + w;
  const int tmin = t0, tmax = t0 + 31;

  // Q fragments in registers (A-operand: m=l31 row, k-octet=l5)
  bf16x8 aq[16];
  {
    const unsigned short* qrow =
        qb + (((size_t)b * 2048 + tmin + l31) * 8 + n) * 256 + l5 * 8;
#pragma unroll
    for (int kc = 0; kc < 16; ++kc) aq[kc] = *(const bf16x8*)(qrow + kc * 16);
  }

  f32x16 O[8], lsum;
#pragma unroll
  for (int i = 0; i < 8; ++i)
#pragma unroll
    for (int r = 0; r < 16; ++r) O[i][r] = 0.f;
#pragma unroll
  for (int r = 0; r < 16; ++r) lsum[r] = 0.f;

  bf16x8 ones;
#pragma unroll
  for (int i = 0; i < 8; ++i) ones[i] = (short)0x3F80;  // bf16 1.0

  const unsigned short* kpb = kpan + (size_t)(b * 4 + kvh) * 64 * 8192;
  const unsigned short* vpb = vpan + (size_t)(b * 4 + kvh) * 64 * 8192;

  int s_lo = t0 - 1024; if (s_lo < 0) s_lo = 0;
  const int s_end = t0 + 32;

  for (int s0 = s_lo; s0 < s_end; s0 += 32) {
    __syncthreads();  // both waves done reading Kl/Vl from previous step
    const unsigned short* kp = kpb + (size_t)(s0 >> 5) * 8192;
    const unsigned short* vp = vpb + (size_t)(s0 >> 5) * 8192;
#pragma unroll
    for (int j = 0; j < 8; ++j) {
      int g = j * 128 + tid;
      GLD16(kp + g * 8, Kl + g * 8);
    }
#pragma unroll
    for (int j = 0; j < 8; ++j) {
      int g = j * 128 + tid;
      GLD16(vp + g * 8, Vl + g * 8);
    }
    __syncthreads();  // staging complete

    // S = Q K^T (two parallel accumulation chains)
    f32x16 pa, pb;
#pragma unroll
    for (int r = 0; r < 16; ++r) { pa[r] = 0.f; pb[r] = 0.f; }
#pragma unroll
    for (int kc = 0; kc < 16; kc += 2) {
      bf16x8 b0 = *(const bf16x8*)&Kl[l31 * 256 + (((kc * 2 + l5) ^ l31) & 31) * 8];
      bf16x8 b1 = *(const bf16x8*)&Kl[l31 * 256 + ((((kc + 1) * 2 + l5) ^ l31) & 31) * 8];
      pa = __builtin_amdgcn_mfma_f32_32x32x16_bf16(aq[kc], b0, pa, 0, 0, 0);
      pb = __builtin_amdgcn_mfma_f32_32x32x16_bf16(aq[kc + 1], b1, pb, 0, 0, 0);
    }

    bool allvalid = (s0 + 31 <= tmin) && (s0 >= tmax - 1023);
    int scol = s0 + l31;
    // P = exp(S), mask -> 0; write to Ps as bf16 (A-layout, wave-private)
#pragma unroll
    for (int r = 0; r < 16; ++r) {
      float sv = pa[r] + pb[r];
      float p = exp2f(sv * 1.442695040888963f);
      int m = (r & 3) + 8 * (r >> 2) + 4 * l5;
      if (!allvalid) {
        int dt = (tmin + m) - scol;
        p = (dt >= 0 && dt < 1024) ? p : 0.f;
      }
      Ps[w * 1536 + (l31 >> 4) * 768 + m * 24 + (l31 & 15)] = f2bf(p);
    }

    // PV + row-sum (wave-private Ps: no barrier needed)
    bf16x8 pf0 = *(const bf16x8*)&Ps[w * 1536 + l31 * 24 + l5 * 8];
    bf16x8 pf1 = *(const bf16x8*)&Ps[w * 1536 + 768 + l31 * 24 + l5 * 8];
    lsum = __builtin_amdgcn_mfma_f32_32x32x16_bf16(pf0, ones, lsum, 0, 0, 0);
    lsum = __builtin_amdgcn_mfma_f32_32x32x16_bf16(pf1, ones, lsum, 0, 0, 0);
#pragma unroll
    for (int hb = 0; hb < 8; ++hb) {
      int row = hb * 32 + l31;
      bf16x8 v0 = *(const bf16x8*)&Vl[row * 32 + ((l5 ^ row) & 3) * 8];
      bf16x8 v1 = *(const bf16x8*)&Vl[row * 32 + (((2 + l5) ^ row) & 3) * 8];
      O[hb] = __builtin_amdgcn_mfma_f32_32x32x16_bf16(pf0, v0, O[hb], 0, 0, 0);
      O[hb] = __builtin_amdgcn_mfma_f32_32x32x16_bf16(pf1, v1, O[hb], 0, 0, 0);
    }
  }

  // epilogue: normalize and store bf16
  unsigned short* obase = ob + (((size_t)b * 2048 + tmin) * 8 + n) * 256;
#pragma unroll
  for (int r = 0; r < 16; ++r) {
    int m = (r & 3) + 8 * (r >> 2) + 4 * l5;
    float rinv = 1.0f / lsum[r];
    size_t rowoff = (size_t)m * 2048;
#pragma unroll
    for (int hb = 0; hb < 8; ++hb)
      obase[rowoff + hb * 32 + l31] = f2bf(O[hb][r] * rinv);
  }
}

extern "C" void kernel_launch(void* const* d_in, const int* in_sizes, int n_in,
                              void* d_out, int out_size, void* d_ws, size_t ws_size,
                              hipStream_t stream) {
  const float* x   = (const float*)d_in[0];
  const int* pos   = (const int*)d_in[1];
  const float* q_w = (const float*)d_in[2];
  const float* k_w = (const float*)d_in[3];
  const float* v_w = (const float*)d_in[4];
  const float* o_w = (const float*)d_in[5];
  const float* qns = (const float*)d_in[6];
  const float* kns = (const float*)d_in[7];
  float* out = (float*)d_out;

  unsigned short* W = (unsigned short*)d_ws;
  unsigned short* qb0   = W;               //  8,388,608 us  q bf16
  unsigned short* kb0   = W + 8388608;     //  4,194,304 us  k bf16 (row-major)
  unsigned short* vbf   = W + 12582912;    //  4,194,304 us  v bf16 (row-major)
  unsigned short* vpan  = W + 16777216;    //  4,194,304 us  v panels (swizzled)
  unsigned short* kpan  = W + 20971520;    //  4,194,304 us  k panels (swizzled)
  unsigned short* xb    = W + 25165824;    //  8,388,608 us  x bf16
  unsigned short* wqkvt = W + 33554432;    //  8,388,608 us  qkv weights^T
  unsigned short* abuf  = wqkvt;           //  reuse after gemm_qkv
  unsigned short* wot   = W + 41943040;    //  4,194,304 us  o weights^T
  // total 46,137,344 us = 92.3 MB

  prep<<<dim3(11264), 256, 0, stream>>>(x, q_w, k_w, v_w, o_w, xb, wqkvt, wot);
  gemm_qkv_bf16<<<dim3(32, 32), 256, 0, stream>>>(xb, wqkvt, qb0, kb0, vbf);
  postproc<<<dim3(13312), 256, 0, stream>>>(qb0, kb0, kpan, vbf, vpan, pos, qns, kns);
  attn_mfma<<<dim3(512), 128, 0, stream>>>(qb0, kpan, vpan, abuf);
  gemm_out_bf16<<<dim3(16, 32), 256, 0, stream>>>(abuf, wot, out);
}